// Round 9
// baseline (1717.798 us; speedup 1.0000x reference)
//
#include <hip/hip_runtime.h>
#include <hip/hip_bf16.h>
#include <math.h>

#define B_ 4
#define T_ 2048
#define M_ 1024
#define H_ 16
#define E_ 8
#define S_ (B_*T_)      // 8192
#define C_ (S_/E_)      // 1024
#define D_ (M_/H_)      // 64
#define F_ (4*M_)       // 4096

typedef unsigned short ushort_t;
typedef __attribute__((ext_vector_type(8))) short bf16x8;
typedef __attribute__((ext_vector_type(4))) float f32x4;

__device__ __forceinline__ float gelu_exact(float x) {
    return 0.5f * x * (1.0f + erff(x * 0.70710678118654752440f));
}

__device__ __forceinline__ unsigned short f2bf(float f) {
    unsigned int u = __float_as_uint(f);
    u = (u + 0x7FFFu + ((u >> 16) & 1u)) >> 16;   // RNE
    return (unsigned short)u;
}

__device__ __forceinline__ float bf2f(unsigned short h) {
    return __uint_as_float(((unsigned)h) << 16);
}

__device__ __forceinline__ void gload_lds16(const void* g, void* l) {
    __builtin_amdgcn_global_load_lds(
        (const __attribute__((address_space(1))) unsigned int*)g,
        (__attribute__((address_space(3))) unsigned int*)l,
        16, 0, 0);
}

__device__ __forceinline__ void lgkm0() {
    asm volatile("s_waitcnt lgkmcnt(0)" ::: "memory");
}

// ---------------------------------------------------------------------------
// LayerNorm (f32 out).
// ---------------------------------------------------------------------------
__global__ __launch_bounds__(256) void ln_kernel(const float* __restrict__ x,
                                                 const float* __restrict__ g,
                                                 const float* __restrict__ bta,
                                                 float* __restrict__ out)
{
    const int row = blockIdx.x;
    const int tid = threadIdx.x;
    const float4 v = reinterpret_cast<const float4*>(x + (size_t)row * M_)[tid];
    float s = v.x + v.y + v.z + v.w;
    __shared__ float red[4];
    #pragma unroll
    for (int off = 32; off > 0; off >>= 1) s += __shfl_down(s, off);
    if ((tid & 63) == 0) red[tid >> 6] = s;
    __syncthreads();
    const float mu = (red[0] + red[1] + red[2] + red[3]) * (1.0f / (float)M_);
    __syncthreads();
    float4 d;
    d.x = v.x - mu; d.y = v.y - mu; d.z = v.z - mu; d.w = v.w - mu;
    float q = d.x*d.x + d.y*d.y + d.z*d.z + d.w*d.w;
    #pragma unroll
    for (int off = 32; off > 0; off >>= 1) q += __shfl_down(q, off);
    if ((tid & 63) == 0) red[tid >> 6] = q;
    __syncthreads();
    const float var  = (red[0] + red[1] + red[2] + red[3]) * (1.0f / (float)M_);
    const float rstd = 1.0f / sqrtf(var + 1e-5f);
    const float4 gv = reinterpret_cast<const float4*>(g)[tid];
    const float4 bv = reinterpret_cast<const float4*>(bta)[tid];
    float4 o;
    o.x = d.x * rstd * gv.x + bv.x;
    o.y = d.y * rstd * gv.y + bv.y;
    o.z = d.z * rstd * gv.z + bv.z;
    o.w = d.w * rstd * gv.w + bv.w;
    reinterpret_cast<float4*>(out + (size_t)row * M_)[tid] = o;
}

// LayerNorm fused with hi/lo bf16 split output.
__global__ __launch_bounds__(256) void ln_split_kernel(const float* __restrict__ x,
                                                       const float* __restrict__ g,
                                                       const float* __restrict__ bta,
                                                       ushort_t* __restrict__ hi,
                                                       ushort_t* __restrict__ lo)
{
    const int row = blockIdx.x;
    const int tid = threadIdx.x;
    const float4 v = reinterpret_cast<const float4*>(x + (size_t)row * M_)[tid];
    float s = v.x + v.y + v.z + v.w;
    __shared__ float red[4];
    #pragma unroll
    for (int off = 32; off > 0; off >>= 1) s += __shfl_down(s, off);
    if ((tid & 63) == 0) red[tid >> 6] = s;
    __syncthreads();
    const float mu = (red[0] + red[1] + red[2] + red[3]) * (1.0f / (float)M_);
    __syncthreads();
    float4 d;
    d.x = v.x - mu; d.y = v.y - mu; d.z = v.z - mu; d.w = v.w - mu;
    float q = d.x*d.x + d.y*d.y + d.z*d.z + d.w*d.w;
    #pragma unroll
    for (int off = 32; off > 0; off >>= 1) q += __shfl_down(q, off);
    if ((tid & 63) == 0) red[tid >> 6] = q;
    __syncthreads();
    const float var  = (red[0] + red[1] + red[2] + red[3]) * (1.0f / (float)M_);
    const float rstd = 1.0f / sqrtf(var + 1e-5f);
    const float4 gv = reinterpret_cast<const float4*>(g)[tid];
    const float4 bv = reinterpret_cast<const float4*>(bta)[tid];
    float o[4];
    o[0] = d.x * rstd * gv.x + bv.x;
    o[1] = d.y * rstd * gv.y + bv.y;
    o[2] = d.z * rstd * gv.z + bv.z;
    o[3] = d.w * rstd * gv.w + bv.w;
    ushort4 hh, ll;
    hh.x = f2bf(o[0]); ll.x = f2bf(o[0] - bf2f(hh.x));
    hh.y = f2bf(o[1]); ll.y = f2bf(o[1] - bf2f(hh.y));
    hh.z = f2bf(o[2]); ll.z = f2bf(o[2] - bf2f(hh.z));
    hh.w = f2bf(o[3]); ll.w = f2bf(o[3] - bf2f(hh.w));
    reinterpret_cast<ushort4*>(hi + (size_t)row * M_)[tid] = hh;
    reinterpret_cast<ushort4*>(lo + (size_t)row * M_)[tid] = ll;
}

// Elementwise f32 -> hi/lo bf16 split (weights).
__global__ __launch_bounds__(256) void split_kernel(const float* __restrict__ in,
                                                    ushort_t* __restrict__ hi,
                                                    ushort_t* __restrict__ lo,
                                                    int n4)
{
    const int i = blockIdx.x * 256 + threadIdx.x;
    if (i >= n4) return;
    const float4 v = reinterpret_cast<const float4*>(in)[i];
    ushort4 hh, ll;
    hh.x = f2bf(v.x); ll.x = f2bf(v.x - bf2f(hh.x));
    hh.y = f2bf(v.y); ll.y = f2bf(v.y - bf2f(hh.y));
    hh.z = f2bf(v.z); ll.z = f2bf(v.z - bf2f(hh.z));
    hh.w = f2bf(v.w); ll.w = f2bf(v.w - bf2f(hh.w));
    reinterpret_cast<ushort4*>(hi)[i] = hh;
    reinterpret_cast<ushort4*>(lo)[i] = ll;
}

// V^T pre-transpose: qkv hi/lo [s][3M] (V slice) -> vt hi/lo [(b*H+h)*64+d][T].
__global__ __launch_bounds__(256) void vtrans_kernel(const ushort_t* __restrict__ qkvh,
                                                     const ushort_t* __restrict__ qkvl,
                                                     ushort_t* __restrict__ vth,
                                                     ushort_t* __restrict__ vtl)
{
    __shared__ ushort_t tile[64][72];
    const int t0 = blockIdx.x * 64, h = blockIdx.y, b = blockIdx.z;
    const int tid = threadIdx.x;
    const int tr = tid & 63, dc = (tid >> 6) * 16;
    const size_t src = ((size_t)(b*T_ + t0 + tr)) * (3*M_) + 2*M_ + h*64 + dc;
    const int dr = tid & 63, tc = (tid >> 6) * 16;
    const size_t dst = ((size_t)((b*H_ + h)*64 + dr)) * T_ + t0 + tc;

    #pragma unroll
    for (int pass = 0; pass < 2; ++pass) {
        const ushort_t* in = pass ? qkvl : qkvh;
        ushort_t* outp     = pass ? vtl  : vth;
        *reinterpret_cast<bf16x8*>(&tile[tr][dc])     = *reinterpret_cast<const bf16x8*>(in + src);
        *reinterpret_cast<bf16x8*>(&tile[tr][dc + 8]) = *reinterpret_cast<const bf16x8*>(in + src + 8);
        __syncthreads();
        bf16x8 o0, o1;
        #pragma unroll
        for (int j = 0; j < 8; ++j) {
            o0[j] = (short)tile[tc + j][dr];
            o1[j] = (short)tile[tc + 8 + j][dr];
        }
        *reinterpret_cast<bf16x8*>(outp + dst)     = o0;
        *reinterpret_cast<bf16x8*>(outp + dst + 8) = o1;
        __syncthreads();
    }
}

// ---------------------------------------------------------------------------
// bf16x3 MFMA GEMM (f32-grade, pre-router). m97 structure, 4 LDS buffers.
// EPI 1: f32 out = acc + bias + res.   EPI 2: hi/lo bf16 out = split(acc+bias).
// ---------------------------------------------------------------------------
template<int EPI>
__global__ __launch_bounds__(256) void gemm_bf16x3(
    const ushort_t* __restrict__ Ahi, const ushort_t* __restrict__ Alo,
    const ushort_t* __restrict__ Bhi, const ushort_t* __restrict__ Blo,
    const float* __restrict__ bias, const float* __restrict__ res,
    void* __restrict__ C0, ushort_t* __restrict__ C1, int N, int K)
{
    __shared__ ushort_t AsH[128*32], AsL[128*32];
    __shared__ ushort_t BsH[128*32], BsL[128*32];

    const int t  = threadIdx.x;
    const int l  = t & 63;
    const int wv = t >> 6;
    const int wm = (wv & 1) * 64, wn = (wv >> 1) * 64;
    const int fr = l & 15, fk = (l >> 4) * 8;
    const int m0 = blockIdx.y * 128, n0 = blockIdx.x * 128;

    const size_t arow = (size_t)(m0 + (t >> 2)) * K + (t & 3) * 8;
    const size_t brow = (size_t)(n0 + (t >> 2)) * K + (t & 3) * 8;
    ushort_t* lAH = AsH + wv * 512;
    ushort_t* lAL = AsL + wv * 512;
    ushort_t* lBH = BsH + wv * 512;
    ushort_t* lBL = BsL + wv * 512;

    f32x4 acc[4][4] = {};

    for (int k0 = 0; k0 < K; k0 += 32) {
        __syncthreads();
        gload_lds16(Ahi + arow + k0, lAH);
        gload_lds16(Ahi + arow + k0 + (size_t)64 * K, lAH + 2048);
        gload_lds16(Alo + arow + k0, lAL);
        gload_lds16(Alo + arow + k0 + (size_t)64 * K, lAL + 2048);
        gload_lds16(Bhi + brow + k0, lBH);
        gload_lds16(Bhi + brow + k0 + (size_t)64 * K, lBH + 2048);
        gload_lds16(Blo + brow + k0, lBL);
        gload_lds16(Blo + brow + k0 + (size_t)64 * K, lBL + 2048);
        __syncthreads();
        bf16x8 ah[4], al[4], bh[4], bl[4];
        #pragma unroll
        for (int i = 0; i < 4; ++i) {
            ah[i] = *reinterpret_cast<const bf16x8*>(&AsH[(wm + i*16 + fr) * 32 + fk]);
            al[i] = *reinterpret_cast<const bf16x8*>(&AsL[(wm + i*16 + fr) * 32 + fk]);
            bh[i] = *reinterpret_cast<const bf16x8*>(&BsH[(wn + i*16 + fr) * 32 + fk]);
            bl[i] = *reinterpret_cast<const bf16x8*>(&BsL[(wn + i*16 + fr) * 32 + fk]);
        }
        #pragma unroll
        for (int mi = 0; mi < 4; ++mi) {
            #pragma unroll
            for (int ni = 0; ni < 4; ++ni) {
                acc[mi][ni] = __builtin_amdgcn_mfma_f32_16x16x32_bf16(ah[mi], bh[ni], acc[mi][ni], 0, 0, 0);
                acc[mi][ni] = __builtin_amdgcn_mfma_f32_16x16x32_bf16(al[mi], bh[ni], acc[mi][ni], 0, 0, 0);
                acc[mi][ni] = __builtin_amdgcn_mfma_f32_16x16x32_bf16(ah[mi], bl[ni], acc[mi][ni], 0, 0, 0);
            }
        }
    }

    // C/D: col = lane&15, row = (lane>>4)*4 + reg
    const int l4 = (l >> 4) * 4;
    #pragma unroll
    for (int mi = 0; mi < 4; ++mi) {
        #pragma unroll
        for (int i = 0; i < 4; ++i) {
            const int row = m0 + wm + mi*16 + l4 + i;
            #pragma unroll
            for (int ni = 0; ni < 4; ++ni) {
                const int col = n0 + wn + ni*16 + fr;
                float v = acc[mi][ni][i] + bias[col];
                if (EPI == 1) {
                    v += res[(size_t)row * N + col];
                    ((float*)C0)[(size_t)row * N + col] = v;
                } else {
                    const ushort_t hb = f2bf(v);
                    ((ushort_t*)C0)[(size_t)row * N + col] = hb;
                    C1[(size_t)row * N + col] = f2bf(v - bf2f(hb));
                }
            }
        }
    }
}

// ---------------------------------------------------------------------------
// bf16x3 MFMA flash attention, QBLK=64, BARRIER-FREE: K and V^T fragments are
// read straight from global (per-lane 16B reads = exact frag pattern; K/V are
// L2/L3-resident with heavy cross-block reuse — m169 pattern). LDS holds only
// the per-wave P buffer. Fragment values and MFMA order identical to round 8.
// Softmax exp via __expf (native v_exp).
// ---------------------------------------------------------------------------
__global__ __launch_bounds__(256) void attn_mfma_kernel(
    const ushort_t* __restrict__ qkvh, const ushort_t* __restrict__ qkvl,
    const ushort_t* __restrict__ vth,  const ushort_t* __restrict__ vtl,
    ushort_t* __restrict__ ohi, ushort_t* __restrict__ olo)
{
    const int qt = (int)gridDim.x - 1 - (int)blockIdx.x;   // longest first
    const int h = blockIdx.y, b = blockIdx.z;
    const int q0 = qt * 64;
    const int t = threadIdx.x;
    const int w = t >> 6, l = t & 63;
    const int r = l & 15, g = l >> 4;
    const size_t rowbase = (size_t)b * T_;
    const int hoff = h * D_;

    __shared__ ushort_t Ph[4*16*72], Pl[4*16*72];   // per-wave P, 18 KiB total

    // Q fragments (A-frag: row = l&15, k = 32ks + 8g + j)
    bf16x8 qh[2], ql[2];
    {
        const size_t qrow = (rowbase + q0 + 16*w + r) * (size_t)(3*M_) + hoff;
        #pragma unroll
        for (int ks = 0; ks < 2; ++ks) {
            qh[ks] = *reinterpret_cast<const bf16x8*>(qkvh + qrow + 32*ks + 8*g);
            ql[ks] = *reinterpret_cast<const bf16x8*>(qkvl + qrow + 32*ks + 8*g);
        }
    }

    // K frag pointers: lane reads K row (kt*64 + 16nf + r), 8 elems at col 8g (+32 ks=1)
    const ushort_t* kph[4];
    const ushort_t* kpl[4];
    #pragma unroll
    for (int nf = 0; nf < 4; ++nf) {
        const size_t off = (rowbase + 16*nf + r) * (size_t)(3*M_) + hoff + M_ + 8*g;
        kph[nf] = qkvh + off;
        kpl[nf] = qkvl + off;
    }
    // V^T frag pointers: lane reads V^T row (16df + r), 8 elems at col kt*64 + 8g (+32 ks=1)
    const ushort_t* vph[4];
    const ushort_t* vpl[4];
    #pragma unroll
    for (int df = 0; df < 4; ++df) {
        const size_t off = ((size_t)((b*H_ + h)*64 + 16*df + r)) * T_ + 8*g;
        vph[df] = vth + off;
        vpl[df] = vtl + off;
    }
    const size_t KSTEP = (size_t)64 * (3*M_);

    f32x4 oa[4] = {};
    float mrow[4] = {-__builtin_inff(), -__builtin_inff(), -__builtin_inff(), -__builtin_inff()};
    float lrow[4] = {};

    for (int kt = 0; kt <= qt; ++kt) {
        // ---- QK^T: S[16 q][64 kv], bf16x3, K frags direct from global ----
        f32x4 sa[4] = {};
        #pragma unroll
        for (int ks = 0; ks < 2; ++ks) {
            bf16x8 kh[4], kl[4];
            #pragma unroll
            for (int nf = 0; nf < 4; ++nf) {
                kh[nf] = *reinterpret_cast<const bf16x8*>(kph[nf] + 32*ks);
                kl[nf] = *reinterpret_cast<const bf16x8*>(kpl[nf] + 32*ks);
            }
            #pragma unroll
            for (int nf = 0; nf < 4; ++nf) {
                sa[nf] = __builtin_amdgcn_mfma_f32_16x16x32_bf16(qh[ks], kh[nf], sa[nf], 0, 0, 0);
                sa[nf] = __builtin_amdgcn_mfma_f32_16x16x32_bf16(ql[ks], kh[nf], sa[nf], 0, 0, 0);
                sa[nf] = __builtin_amdgcn_mfma_f32_16x16x32_bf16(qh[ks], kl[nf], sa[nf], 0, 0, 0);
            }
        }

        // ---- scale + causal mask ----
        float sv[4][4];
        #pragma unroll
        for (int nf = 0; nf < 4; ++nf)
            #pragma unroll
            for (int i = 0; i < 4; ++i)
                sv[nf][i] = sa[nf][i] * 0.125f;
        if (kt == qt) {
            #pragma unroll
            for (int nf = 0; nf < 4; ++nf) {
                const int kvg = kt*64 + 16*nf + r;
                #pragma unroll
                for (int i = 0; i < 4; ++i) {
                    const int qg = q0 + 16*w + 4*g + i;
                    if (kvg > qg) sv[nf][i] = -3.0e38f;
                }
            }
        }

        // ---- online softmax (native exp) ----
        float tmax[4];
        #pragma unroll
        for (int i = 0; i < 4; ++i)
            tmax[i] = fmaxf(fmaxf(sv[0][i], sv[1][i]), fmaxf(sv[2][i], sv[3][i]));
        #pragma unroll
        for (int off = 1; off < 16; off <<= 1)
            #pragma unroll
            for (int i = 0; i < 4; ++i)
                tmax[i] = fmaxf(tmax[i], __shfl_xor(tmax[i], off));
        float mnew[4], corr[4];
        #pragma unroll
        for (int i = 0; i < 4; ++i) {
            mnew[i] = fmaxf(mrow[i], tmax[i]);
            corr[i] = __expf(mrow[i] - mnew[i]);
        }
        float p[4][4];
        float rsum[4] = {};
        #pragma unroll
        for (int nf = 0; nf < 4; ++nf)
            #pragma unroll
            for (int i = 0; i < 4; ++i) {
                p[nf][i] = __expf(sv[nf][i] - mnew[i]);
                rsum[i] += p[nf][i];
            }
        #pragma unroll
        for (int off = 1; off < 16; off <<= 1)
            #pragma unroll
            for (int i = 0; i < 4; ++i)
                rsum[i] += __shfl_xor(rsum[i], off);
        #pragma unroll
        for (int i = 0; i < 4; ++i) {
            lrow[i] = lrow[i] * corr[i] + rsum[i];
            mrow[i] = mnew[i];
        }
        #pragma unroll
        for (int df = 0; df < 4; ++df)
            #pragma unroll
            for (int i = 0; i < 4; ++i)
                oa[df][i] *= corr[i];

        // ---- write P (per-wave [16 q][72 kv], hi/lo) ----
        #pragma unroll
        for (int nf = 0; nf < 4; ++nf) {
            const int kv = 16*nf + r;
            #pragma unroll
            for (int i = 0; i < 4; ++i) {
                const ushort_t phb = f2bf(p[nf][i]);
                Ph[(w*16 + 4*g + i) * 72 + kv] = phb;
                Pl[(w*16 + 4*g + i) * 72 + kv] = f2bf(p[nf][i] - bf2f(phb));
            }
        }
        lgkm0();   // P writes visible to this wave's reads (per-wave buffer)

        // ---- PV: O += P·V, bf16x3, V frags direct from global ----
        #pragma unroll
        for (int ks = 0; ks < 2; ++ks) {
            const bf16x8 ph = *reinterpret_cast<const bf16x8*>(&Ph[(w*16 + r) * 72 + 32*ks + 8*g]);
            const bf16x8 pl = *reinterpret_cast<const bf16x8*>(&Pl[(w*16 + r) * 72 + 32*ks + 8*g]);
            #pragma unroll
            for (int df = 0; df < 4; ++df) {
                const bf16x8 vhf = *reinterpret_cast<const bf16x8*>(vph[df] + 32*ks);
                const bf16x8 vlf = *reinterpret_cast<const bf16x8*>(vpl[df] + 32*ks);
                oa[df] = __builtin_amdgcn_mfma_f32_16x16x32_bf16(ph, vhf, oa[df], 0, 0, 0);
                oa[df] = __builtin_amdgcn_mfma_f32_16x16x32_bf16(pl, vhf, oa[df], 0, 0, 0);
                oa[df] = __builtin_amdgcn_mfma_f32_16x16x32_bf16(ph, vlf, oa[df], 0, 0, 0);
            }
        }

        // advance K/V pointers to next kv tile
        #pragma unroll
        for (int nf = 0; nf < 4; ++nf) { kph[nf] += KSTEP; kpl[nf] += KSTEP; }
        #pragma unroll
        for (int df = 0; df < 4; ++df) { vph[df] += 64; vpl[df] += 64; }
    }

    // ---- epilogue: hi/lo split of O / l ----
    #pragma unroll
    for (int i = 0; i < 4; ++i) {
        const float inv = 1.0f / lrow[i];
        const size_t row = (rowbase + q0 + 16*w + 4*g + i) * (size_t)M_ + hoff;
        #pragma unroll
        for (int df = 0; df < 4; ++df) {
            const float v = oa[df][i] * inv;
            const ushort_t hb = f2bf(v);
            ohi[row + 16*df + r] = hb;
            olo[row + 16*df + r] = f2bf(v - bf2f(hb));
        }
    }
}

// ---------------------------------------------------------------------------
// Router + deepspeed dispatch bookkeeping (exact, f32).
// ---------------------------------------------------------------------------
__global__ __launch_bounds__(256) void gate_kernel(const float* __restrict__ h2,
                                                   const float* __restrict__ wg,
                                                   int* __restrict__ gidx,
                                                   float* __restrict__ gtop)
{
    const int s = blockIdx.x;
    const int e = threadIdx.x >> 5;
    const int l = threadIdx.x & 31;
    const float* row = h2 + (size_t)s * M_;
    float acc = 0.0f;
    for (int m = l; m < M_; m += 32) acc = fmaf(row[m], wg[m * E_ + e], acc);
    #pragma unroll
    for (int off = 16; off > 0; off >>= 1) acc += __shfl_down(acc, off, 32);
    __shared__ float lg[E_];
    if (l == 0) lg[e] = acc;
    __syncthreads();
    if (threadIdx.x == 0) {
        float mx = lg[0]; int bi = 0;
        #pragma unroll
        for (int i = 1; i < E_; ++i) { if (lg[i] > mx) { mx = lg[i]; bi = i; } }
        float den = 0.0f;
        #pragma unroll
        for (int i = 0; i < E_; ++i) den += expf(lg[i] - mx);
        gidx[s] = bi;
        gtop[s] = 1.0f / den;
    }
}

__global__ __launch_bounds__(1024) void scan_kernel(const int* __restrict__ gidx,
                                                    const float* __restrict__ gtop,
                                                    float* __restrict__ gate_val,
                                                    int* __restrict__ token_at)
{
    __shared__ int hist[1024][E_];
    const int tid = threadIdx.x;
    for (int i = tid; i < E_ * C_; i += 1024) token_at[i] = -1;
    int my[8];
    #pragma unroll
    for (int t = 0; t < 8; ++t) my[t] = gidx[tid * 8 + t];
    #pragma unroll
    for (int e = 0; e < E_; ++e) {
        int c = 0;
        #pragma unroll
        for (int t = 0; t < 8; ++t) c += (my[t] == e) ? 1 : 0;
        hist[tid][e] = c;
    }
    __syncthreads();
    if (tid < E_) {
        int run = 0;
        for (int t = 0; t < 1024; ++t) {
            const int v = hist[t][tid];
            hist[t][tid] = run;
            run += v;
        }
    }
    __syncthreads();
    #pragma unroll
    for (int t = 0; t < 8; ++t) {
        const int s = tid * 8 + t;
        const int e = my[t];
        const int p = hist[tid][e];
        hist[tid][e] = p + 1;
        const bool keep = (p < C_);
        gate_val[s] = keep ? gtop[s] : 0.0f;
        if (keep) token_at[e * C_ + p] = s;
    }
}

__global__ __launch_bounds__(256) void dispatch_bf16_kernel(const float* __restrict__ h2,
                                                            const int* __restrict__ token_at,
                                                            ushort_t* __restrict__ disp)
{
    const int ec = blockIdx.x;
    const int s = token_at[ec];
    ushort4* dst = reinterpret_cast<ushort4*>(disp + (size_t)ec * M_);
    if (s >= 0) {
        const float4 v = reinterpret_cast<const float4*>(h2 + (size_t)s * M_)[threadIdx.x];
        dst[threadIdx.x] = make_ushort4(f2bf(v.x), f2bf(v.y), f2bf(v.z), f2bf(v.w));
    } else {
        dst[threadIdx.x] = make_ushort4(0, 0, 0, 0);
    }
}

// Transpose+convert: in[e][R][Cc] f32 -> out[e][Cc][R] bf16.
__global__ __launch_bounds__(256) void transpose_bf16_kernel(const float* __restrict__ in,
                                                             ushort_t* __restrict__ outp,
                                                             int R, int Cc)
{
    __shared__ float tile[32][33];
    const int e = blockIdx.z;
    in   += (size_t)e * R * Cc;
    outp += (size_t)e * R * Cc;
    const int tx = threadIdx.x & 31, ty0 = threadIdx.x >> 5;
    const int c0 = blockIdx.x * 32, r0 = blockIdx.y * 32;
    #pragma unroll
    for (int i = 0; i < 4; ++i)
        tile[ty0 + 8*i][tx] = in[(size_t)(r0 + ty0 + 8*i) * Cc + c0 + tx];
    __syncthreads();
    #pragma unroll
    for (int i = 0; i < 4; ++i)
        outp[(size_t)(c0 + ty0 + 8*i) * R + r0 + tx] = f2bf(tile[tx][ty0 + 8*i]);
}

// ---------------------------------------------------------------------------
// bf16 MFMA GEMM (MoE FFN, post-router) — unchanged, verified.
// ---------------------------------------------------------------------------
template<int EPI>
__global__ __launch_bounds__(256) void gemm_mfma(
    const ushort_t* __restrict__ A, const ushort_t* __restrict__ Bt,
    const float* __restrict__ bias,
    const int* __restrict__ token_at, const float* __restrict__ gate_val,
    void* __restrict__ Cout, int N, int K,
    long strA, long strB, long strBias, long strC)
{
    const int e = blockIdx.z;
    A    += (size_t)e * (size_t)strA;
    Bt   += (size_t)e * (size_t)strB;
    bias += (size_t)e * (size_t)strBias;

    __shared__ ushort_t As[128 * 32];
    __shared__ ushort_t Bs[128 * 32];

    const int t  = threadIdx.x;
    const int l  = t & 63;
    const int wv = t >> 6;
    const int wm = (wv & 1) * 64, wn = (wv >> 1) * 64;
    const int fr = l & 15, fk = (l >> 4) * 8;
    const int m0 = blockIdx.y * 128, n0 = blockIdx.x * 128;

    const ushort_t* gA = A + (size_t)(m0 + (t >> 2)) * K + (t & 3) * 8;
    const ushort_t* gB = Bt + (size_t)(n0 + (t >> 2)) * K + (t & 3) * 8;
    ushort_t* lA = As + wv * 512;
    ushort_t* lB = Bs + wv * 512;

    f32x4 acc[4][4] = {};

    for (int k0 = 0; k0 < K; k0 += 32) {
        __syncthreads();
        gload_lds16(gA + k0, lA);
        gload_lds16(gA + k0 + (size_t)64 * K, lA + 2048);
        gload_lds16(gB + k0, lB);
        gload_lds16(gB + k0 + (size_t)64 * K, lB + 2048);
        __syncthreads();
        bf16x8 af[4], bfr[4];
        #pragma unroll
        for (int i = 0; i < 4; ++i)
            af[i] = *reinterpret_cast<const bf16x8*>(&As[(wm + i*16 + fr) * 32 + fk]);
        #pragma unroll
        for (int i = 0; i < 4; ++i)
            bfr[i] = *reinterpret_cast<const bf16x8*>(&Bs[(wn + i*16 + fr) * 32 + fk]);
        #pragma unroll
        for (int mi = 0; mi < 4; ++mi) {
            #pragma unroll
            for (int ni = 0; ni < 4; ++ni)
                acc[mi][ni] = __builtin_amdgcn_mfma_f32_16x16x32_bf16(
                    af[mi], bfr[ni], acc[mi][ni], 0, 0, 0);
        }
    }

    const int l4 = (l >> 4) * 4;
    if (EPI == 0) {
        ushort_t* Cc = (ushort_t*)Cout + (size_t)e * (size_t)strC;
        #pragma unroll
        for (int ni = 0; ni < 4; ++ni) {
            const int cl = n0 + wn + ni*16 + fr;
            const float bb = bias[cl];
            #pragma unroll
            for (int mi = 0; mi < 4; ++mi) {
                #pragma unroll
                for (int i = 0; i < 4; ++i) {
                    const int rr = m0 + wm + mi*16 + l4 + i;
                    Cc[(size_t)rr * N + cl] = f2bf(gelu_exact(acc[mi][ni][i] + bb));
                }
            }
        }
    } else {
        float* Co = (float*)Cout;
        const int* ta = token_at + e * C_;
        #pragma unroll
        for (int mi = 0; mi < 4; ++mi) {
            #pragma unroll
            for (int i = 0; i < 4; ++i) {
                const int rr = m0 + wm + mi*16 + l4 + i;
                const int s = ta[rr];
                if (s >= 0) {
                    const float gvl = gate_val[s];
                    #pragma unroll
                    for (int ni = 0; ni < 4; ++ni) {
                        const int cl = n0 + wn + ni*16 + fr;
                        Co[(size_t)s * N + cl] += gvl * (acc[mi][ni][i] + bias[cl]);
                    }
                }
            }
        }
    }
}

// ---------------------------------------------------------------------------
extern "C" void kernel_launch(void* const* d_in, const int* in_sizes, int n_in,
                              void* d_out, int out_size, void* d_ws, size_t ws_size,
                              hipStream_t stream)
{
    const float* x    = (const float*)d_in[0];
    const float* ln1g = (const float*)d_in[1];
    const float* ln1b = (const float*)d_in[2];
    const float* Wqkv = (const float*)d_in[3];
    const float* bqkv = (const float*)d_in[4];
    const float* Wout = (const float*)d_in[5];
    const float* bout = (const float*)d_in[6];
    const float* ln2g = (const float*)d_in[7];
    const float* ln2b = (const float*)d_in[8];
    const float* wg   = (const float*)d_in[9];
    const float* w1   = (const float*)d_in[10];
    const float* b1   = (const float*)d_in[11];
    const float* w2   = (const float*)d_in[12];
    const float* b2   = (const float*)d_in[13];
    float* out = (float*)d_out;

    // Workspace (MiB offsets), lifetime-scheduled. Peak ~196 MiB.
    char* ws = (char*)d_ws;
    ushort_t* ahi   = (ushort_t*)ws;
    ushort_t* alo   = (ushort_t*)(ws + ((size_t)16  << 20));
    float*    buf_h = (float*)ws;
    ushort_t* qkvh  = (ushort_t*)(ws + ((size_t)32  << 20));
    ushort_t* qkvl  = (ushort_t*)(ws + ((size_t)80  << 20));
    ushort_t* vth   = (ushort_t*)(ws + ((size_t)128 << 20));
    ushort_t* vtl   = (ushort_t*)(ws + ((size_t)144 << 20));
    ushort_t* ohi   = (ushort_t*)(ws + ((size_t)160 << 20));
    ushort_t* olo   = (ushort_t*)(ws + ((size_t)176 << 20));
    ushort_t* wqh   = (ushort_t*)(ws + ((size_t)128 << 20));   // ph1 only
    ushort_t* wql   = (ushort_t*)(ws + ((size_t)134 << 20));   // ph1 only
    ushort_t* woh   = (ushort_t*)(ws + ((size_t)192 << 20));
    ushort_t* wol   = (ushort_t*)(ws + ((size_t)194 << 20));
    ushort_t* w1t   = (ushort_t*)(ws + ((size_t)32  << 20));
    ushort_t* w2t   = (ushort_t*)(ws + ((size_t)32  << 20));
    ushort_t* dispb = (ushort_t*)(ws + ((size_t)96  << 20));
    ushort_t* h1b   = (ushort_t*)(ws + ((size_t)112 << 20));
    float*    buf_gtop = (float*)(ws + ((size_t)196 << 20));
    float*    buf_gv   = buf_gtop + S_;
    int*      buf_idx  = (int*)(buf_gv + S_);
    int*      buf_ta   = buf_idx + S_;

    // --- pre-router path (f32-grade via bf16x3 MFMA) ---
    split_kernel<<<(3*M_*M_/4 + 255)/256, 256, 0, stream>>>(Wqkv, wqh, wql, 3*M_*M_/4);
    split_kernel<<<(M_*M_/4 + 255)/256, 256, 0, stream>>>(Wout, woh, wol, M_*M_/4);
    ln_split_kernel<<<S_, 256, 0, stream>>>(x, ln1g, ln1b, ahi, alo);
    gemm_bf16x3<2><<<dim3(3*M_/128, S_/128, 1), 256, 0, stream>>>(
        ahi, alo, wqh, wql, bqkv, nullptr, qkvh, qkvl, 3*M_, M_);
    vtrans_kernel<<<dim3(T_/64, H_, B_), 256, 0, stream>>>(qkvh, qkvl, vth, vtl);
    attn_mfma_kernel<<<dim3(T_/64, H_, B_), 256, 0, stream>>>(qkvh, qkvl, vth, vtl, ohi, olo);
    gemm_bf16x3<1><<<dim3(M_/128, S_/128, 1), 256, 0, stream>>>(
        ohi, olo, woh, wol, bout, x, out, nullptr, M_, M_);

    // --- router (exact f32) ---
    ln_kernel<<<S_, 256, 0, stream>>>(out, ln2g, ln2b, buf_h);
    gate_kernel<<<S_, 256, 0, stream>>>(buf_h, wg, buf_idx, buf_gtop);
    scan_kernel<<<1, 1024, 0, stream>>>(buf_idx, buf_gtop, buf_gv, buf_ta);
    dispatch_bf16_kernel<<<E_*C_, 256, 0, stream>>>(buf_h, buf_ta, dispb);

    // --- MoE FFN (bf16 MFMA, post-router) ---
    transpose_bf16_kernel<<<dim3(F_/32, M_/32, E_), 256, 0, stream>>>(w1, w1t, M_, F_);
    gemm_mfma<0><<<dim3(F_/128, C_/128, E_), 256, 0, stream>>>(
        dispb, w1t, b1, nullptr, nullptr, h1b, F_, M_,
        (long)C_*M_, (long)F_*M_, (long)F_, (long)C_*F_);
    transpose_bf16_kernel<<<dim3(M_/32, F_/32, E_), 256, 0, stream>>>(w2, w2t, F_, M_);
    gemm_mfma<1><<<dim3(M_/128, C_/128, E_), 256, 0, stream>>>(
        h1b, w2t, b2, buf_ta, buf_gv, out, M_, F_,
        (long)C_*F_, (long)M_*F_, (long)M_, 0);
}

// Round 10
// 1147.422 us; speedup vs baseline: 1.4971x; 1.4971x over previous
//
#include <hip/hip_runtime.h>
#include <hip/hip_bf16.h>
#include <math.h>

#define B_ 4
#define T_ 2048
#define M_ 1024
#define H_ 16
#define E_ 8
#define S_ (B_*T_)      // 8192
#define C_ (S_/E_)      // 1024
#define D_ (M_/H_)      // 64
#define F_ (4*M_)       // 4096

typedef unsigned short ushort_t;
typedef __attribute__((ext_vector_type(8))) short bf16x8;
typedef __attribute__((ext_vector_type(4))) float f32x4;

__device__ __forceinline__ float gelu_exact(float x) {
    return 0.5f * x * (1.0f + erff(x * 0.70710678118654752440f));
}

__device__ __forceinline__ unsigned short f2bf(float f) {
    unsigned int u = __float_as_uint(f);
    u = (u + 0x7FFFu + ((u >> 16) & 1u)) >> 16;   // RNE
    return (unsigned short)u;
}

__device__ __forceinline__ float bf2f(unsigned short h) {
    return __uint_as_float(((unsigned)h) << 16);
}

__device__ __forceinline__ void gload_lds16(const void* g, void* l) {
    __builtin_amdgcn_global_load_lds(
        (const __attribute__((address_space(1))) unsigned int*)g,
        (__attribute__((address_space(3))) unsigned int*)l,
        16, 0, 0);
}

__device__ __forceinline__ void lgkm0() {
    asm volatile("s_waitcnt lgkmcnt(0)" ::: "memory");
}

// ---------------------------------------------------------------------------
// LayerNorm (f32 out).
// ---------------------------------------------------------------------------
__global__ __launch_bounds__(256) void ln_kernel(const float* __restrict__ x,
                                                 const float* __restrict__ g,
                                                 const float* __restrict__ bta,
                                                 float* __restrict__ out)
{
    const int row = blockIdx.x;
    const int tid = threadIdx.x;
    const float4 v = reinterpret_cast<const float4*>(x + (size_t)row * M_)[tid];
    float s = v.x + v.y + v.z + v.w;
    __shared__ float red[4];
    #pragma unroll
    for (int off = 32; off > 0; off >>= 1) s += __shfl_down(s, off);
    if ((tid & 63) == 0) red[tid >> 6] = s;
    __syncthreads();
    const float mu = (red[0] + red[1] + red[2] + red[3]) * (1.0f / (float)M_);
    __syncthreads();
    float4 d;
    d.x = v.x - mu; d.y = v.y - mu; d.z = v.z - mu; d.w = v.w - mu;
    float q = d.x*d.x + d.y*d.y + d.z*d.z + d.w*d.w;
    #pragma unroll
    for (int off = 32; off > 0; off >>= 1) q += __shfl_down(q, off);
    if ((tid & 63) == 0) red[tid >> 6] = q;
    __syncthreads();
    const float var  = (red[0] + red[1] + red[2] + red[3]) * (1.0f / (float)M_);
    const float rstd = 1.0f / sqrtf(var + 1e-5f);
    const float4 gv = reinterpret_cast<const float4*>(g)[tid];
    const float4 bv = reinterpret_cast<const float4*>(bta)[tid];
    float4 o;
    o.x = d.x * rstd * gv.x + bv.x;
    o.y = d.y * rstd * gv.y + bv.y;
    o.z = d.z * rstd * gv.z + bv.z;
    o.w = d.w * rstd * gv.w + bv.w;
    reinterpret_cast<float4*>(out + (size_t)row * M_)[tid] = o;
}

// LayerNorm fused with hi/lo bf16 split output.
__global__ __launch_bounds__(256) void ln_split_kernel(const float* __restrict__ x,
                                                       const float* __restrict__ g,
                                                       const float* __restrict__ bta,
                                                       ushort_t* __restrict__ hi,
                                                       ushort_t* __restrict__ lo)
{
    const int row = blockIdx.x;
    const int tid = threadIdx.x;
    const float4 v = reinterpret_cast<const float4*>(x + (size_t)row * M_)[tid];
    float s = v.x + v.y + v.z + v.w;
    __shared__ float red[4];
    #pragma unroll
    for (int off = 32; off > 0; off >>= 1) s += __shfl_down(s, off);
    if ((tid & 63) == 0) red[tid >> 6] = s;
    __syncthreads();
    const float mu = (red[0] + red[1] + red[2] + red[3]) * (1.0f / (float)M_);
    __syncthreads();
    float4 d;
    d.x = v.x - mu; d.y = v.y - mu; d.z = v.z - mu; d.w = v.w - mu;
    float q = d.x*d.x + d.y*d.y + d.z*d.z + d.w*d.w;
    #pragma unroll
    for (int off = 32; off > 0; off >>= 1) q += __shfl_down(q, off);
    if ((tid & 63) == 0) red[tid >> 6] = q;
    __syncthreads();
    const float var  = (red[0] + red[1] + red[2] + red[3]) * (1.0f / (float)M_);
    const float rstd = 1.0f / sqrtf(var + 1e-5f);
    const float4 gv = reinterpret_cast<const float4*>(g)[tid];
    const float4 bv = reinterpret_cast<const float4*>(bta)[tid];
    float o[4];
    o[0] = d.x * rstd * gv.x + bv.x;
    o[1] = d.y * rstd * gv.y + bv.y;
    o[2] = d.z * rstd * gv.z + bv.z;
    o[3] = d.w * rstd * gv.w + bv.w;
    ushort4 hh, ll;
    hh.x = f2bf(o[0]); ll.x = f2bf(o[0] - bf2f(hh.x));
    hh.y = f2bf(o[1]); ll.y = f2bf(o[1] - bf2f(hh.y));
    hh.z = f2bf(o[2]); ll.z = f2bf(o[2] - bf2f(hh.z));
    hh.w = f2bf(o[3]); ll.w = f2bf(o[3] - bf2f(hh.w));
    reinterpret_cast<ushort4*>(hi + (size_t)row * M_)[tid] = hh;
    reinterpret_cast<ushort4*>(lo + (size_t)row * M_)[tid] = ll;
}

// Elementwise f32 -> hi/lo bf16 split (weights).
__global__ __launch_bounds__(256) void split_kernel(const float* __restrict__ in,
                                                    ushort_t* __restrict__ hi,
                                                    ushort_t* __restrict__ lo,
                                                    int n4)
{
    const int i = blockIdx.x * 256 + threadIdx.x;
    if (i >= n4) return;
    const float4 v = reinterpret_cast<const float4*>(in)[i];
    ushort4 hh, ll;
    hh.x = f2bf(v.x); ll.x = f2bf(v.x - bf2f(hh.x));
    hh.y = f2bf(v.y); ll.y = f2bf(v.y - bf2f(hh.y));
    hh.z = f2bf(v.z); ll.z = f2bf(v.z - bf2f(hh.z));
    hh.w = f2bf(v.w); ll.w = f2bf(v.w - bf2f(hh.w));
    reinterpret_cast<ushort4*>(hi)[i] = hh;
    reinterpret_cast<ushort4*>(lo)[i] = ll;
}

// V^T pre-transpose: qkv hi/lo [s][3M] (V slice) -> vt hi/lo [(b*H+h)*64+d][T].
__global__ __launch_bounds__(256) void vtrans_kernel(const ushort_t* __restrict__ qkvh,
                                                     const ushort_t* __restrict__ qkvl,
                                                     ushort_t* __restrict__ vth,
                                                     ushort_t* __restrict__ vtl)
{
    __shared__ ushort_t tile[64][72];
    const int t0 = blockIdx.x * 64, h = blockIdx.y, b = blockIdx.z;
    const int tid = threadIdx.x;
    const int tr = tid & 63, dc = (tid >> 6) * 16;
    const size_t src = ((size_t)(b*T_ + t0 + tr)) * (3*M_) + 2*M_ + h*64 + dc;
    const int dr = tid & 63, tc = (tid >> 6) * 16;
    const size_t dst = ((size_t)((b*H_ + h)*64 + dr)) * T_ + t0 + tc;

    #pragma unroll
    for (int pass = 0; pass < 2; ++pass) {
        const ushort_t* in = pass ? qkvl : qkvh;
        ushort_t* outp     = pass ? vtl  : vth;
        *reinterpret_cast<bf16x8*>(&tile[tr][dc])     = *reinterpret_cast<const bf16x8*>(in + src);
        *reinterpret_cast<bf16x8*>(&tile[tr][dc + 8]) = *reinterpret_cast<const bf16x8*>(in + src + 8);
        __syncthreads();
        bf16x8 o0, o1;
        #pragma unroll
        for (int j = 0; j < 8; ++j) {
            o0[j] = (short)tile[tc + j][dr];
            o1[j] = (short)tile[tc + 8 + j][dr];
        }
        *reinterpret_cast<bf16x8*>(outp + dst)     = o0;
        *reinterpret_cast<bf16x8*>(outp + dst + 8) = o1;
        __syncthreads();
    }
}

// ---------------------------------------------------------------------------
// bf16x3 MFMA GEMM (f32-grade, pre-router). m97 structure, 4 LDS buffers.
// EPI 1: f32 out = acc + bias + res.   EPI 2: hi/lo bf16 out = split(acc+bias).
// ---------------------------------------------------------------------------
template<int EPI>
__global__ __launch_bounds__(256) void gemm_bf16x3(
    const ushort_t* __restrict__ Ahi, const ushort_t* __restrict__ Alo,
    const ushort_t* __restrict__ Bhi, const ushort_t* __restrict__ Blo,
    const float* __restrict__ bias, const float* __restrict__ res,
    void* __restrict__ C0, ushort_t* __restrict__ C1, int N, int K)
{
    __shared__ ushort_t AsH[128*32], AsL[128*32];
    __shared__ ushort_t BsH[128*32], BsL[128*32];

    const int t  = threadIdx.x;
    const int l  = t & 63;
    const int wv = t >> 6;
    const int wm = (wv & 1) * 64, wn = (wv >> 1) * 64;
    const int fr = l & 15, fk = (l >> 4) * 8;
    const int m0 = blockIdx.y * 128, n0 = blockIdx.x * 128;

    const size_t arow = (size_t)(m0 + (t >> 2)) * K + (t & 3) * 8;
    const size_t brow = (size_t)(n0 + (t >> 2)) * K + (t & 3) * 8;
    ushort_t* lAH = AsH + wv * 512;
    ushort_t* lAL = AsL + wv * 512;
    ushort_t* lBH = BsH + wv * 512;
    ushort_t* lBL = BsL + wv * 512;

    f32x4 acc[4][4] = {};

    for (int k0 = 0; k0 < K; k0 += 32) {
        __syncthreads();
        gload_lds16(Ahi + arow + k0, lAH);
        gload_lds16(Ahi + arow + k0 + (size_t)64 * K, lAH + 2048);
        gload_lds16(Alo + arow + k0, lAL);
        gload_lds16(Alo + arow + k0 + (size_t)64 * K, lAL + 2048);
        gload_lds16(Bhi + brow + k0, lBH);
        gload_lds16(Bhi + brow + k0 + (size_t)64 * K, lBH + 2048);
        gload_lds16(Blo + brow + k0, lBL);
        gload_lds16(Blo + brow + k0 + (size_t)64 * K, lBL + 2048);
        __syncthreads();
        bf16x8 ah[4], al[4], bh[4], bl[4];
        #pragma unroll
        for (int i = 0; i < 4; ++i) {
            ah[i] = *reinterpret_cast<const bf16x8*>(&AsH[(wm + i*16 + fr) * 32 + fk]);
            al[i] = *reinterpret_cast<const bf16x8*>(&AsL[(wm + i*16 + fr) * 32 + fk]);
            bh[i] = *reinterpret_cast<const bf16x8*>(&BsH[(wn + i*16 + fr) * 32 + fk]);
            bl[i] = *reinterpret_cast<const bf16x8*>(&BsL[(wn + i*16 + fr) * 32 + fk]);
        }
        #pragma unroll
        for (int mi = 0; mi < 4; ++mi) {
            #pragma unroll
            for (int ni = 0; ni < 4; ++ni) {
                acc[mi][ni] = __builtin_amdgcn_mfma_f32_16x16x32_bf16(ah[mi], bh[ni], acc[mi][ni], 0, 0, 0);
                acc[mi][ni] = __builtin_amdgcn_mfma_f32_16x16x32_bf16(al[mi], bh[ni], acc[mi][ni], 0, 0, 0);
                acc[mi][ni] = __builtin_amdgcn_mfma_f32_16x16x32_bf16(ah[mi], bl[ni], acc[mi][ni], 0, 0, 0);
            }
        }
    }

    // C/D: col = lane&15, row = (lane>>4)*4 + reg
    const int l4 = (l >> 4) * 4;
    #pragma unroll
    for (int mi = 0; mi < 4; ++mi) {
        #pragma unroll
        for (int i = 0; i < 4; ++i) {
            const int row = m0 + wm + mi*16 + l4 + i;
            #pragma unroll
            for (int ni = 0; ni < 4; ++ni) {
                const int col = n0 + wn + ni*16 + fr;
                float v = acc[mi][ni][i] + bias[col];
                if (EPI == 1) {
                    v += res[(size_t)row * N + col];
                    ((float*)C0)[(size_t)row * N + col] = v;
                } else {
                    const ushort_t hb = f2bf(v);
                    ((ushort_t*)C0)[(size_t)row * N + col] = hb;
                    C1[(size_t)row * N + col] = f2bf(v - bf2f(hb));
                }
            }
        }
    }
}

// ---------------------------------------------------------------------------
// bf16x3 MFMA flash attention, QBLK=64, LDS-staged (round-8 structure,
// verified 413 µs) + T14 async-STAGE split: tile t+1's K/V are loaded into
// REGISTERS right after tile t's QK^T (HBM latency hides under softmax+PV),
// then written to LDS after the post-PV barrier. LDS image identical to the
// gload_lds path (pre-swizzled source, dest = w*1024 + l*16 bytes).
// Fragment values and MFMA order identical to rounds 6/8. __expf verified r9.
// ---------------------------------------------------------------------------
__global__ __launch_bounds__(256) void attn_mfma_kernel(
    const ushort_t* __restrict__ qkvh, const ushort_t* __restrict__ qkvl,
    const ushort_t* __restrict__ vth,  const ushort_t* __restrict__ vtl,
    ushort_t* __restrict__ ohi, ushort_t* __restrict__ olo)
{
    const int qt = (int)gridDim.x - 1 - (int)blockIdx.x;   // longest first
    const int h = blockIdx.y, b = blockIdx.z;
    const int q0 = qt * 64;
    const int t = threadIdx.x;
    const int w = t >> 6, l = t & 63;
    const int r = l & 15, g = l >> 4;
    const size_t rowbase = (size_t)b * T_;
    const int hoff = h * D_;

    __shared__ ushort_t Khi[64*64], Klo[64*64];   // [kv][64] swizzled
    __shared__ ushort_t Vhi[64*64], Vlo[64*64];   // V^T [d][64 kv] swizzled
    __shared__ ushort_t Ph[4*16*72], Pl[4*16*72];

    // Q fragments (A-frag: row = l&15, k = 32ks + 8g + j)
    bf16x8 qh[2], ql[2];
    {
        const size_t qrow = (rowbase + q0 + 16*w + r) * (size_t)(3*M_) + hoff;
        #pragma unroll
        for (int ks = 0; ks < 2; ++ks) {
            qh[ks] = *reinterpret_cast<const bf16x8*>(qkvh + qrow + 32*ks + 8*g);
            ql[ks] = *reinterpret_cast<const bf16x8*>(qkvl + qrow + 32*ks + 8*g);
        }
    }

    // staging: lane covers LDS row = w*8 + c*32 + (l>>3), bytes (l&7)*16;
    // source col = ((l&7) ^ (l>>3)) * 8 elems -> LDS[row][c'] = G[row][c'^((row&7)<<4B)]
    const int srow = w*8 + (l >> 3);
    const int scol = ((l & 7) ^ (l >> 3)) * 8;
    const size_t ksrc0 = (rowbase + srow) * (size_t)(3*M_) + hoff + M_ + scol;
    const size_t vsrc0 = ((size_t)((b*H_ + h)*64 + srow)) * T_ + scol;
    const int d0 = w * 512 + l * 8;                // ushort index; +2048 = rows+32

    bf16x8 stg[8];
    // prologue: stage tile 0
    {
        const size_t kb = ksrc0, vb = vsrc0;
        const size_t kstep = (size_t)32 * (3*M_);
        stg[0] = *reinterpret_cast<const bf16x8*>(qkvh + kb);
        stg[1] = *reinterpret_cast<const bf16x8*>(qkvh + kb + kstep);
        stg[2] = *reinterpret_cast<const bf16x8*>(qkvl + kb);
        stg[3] = *reinterpret_cast<const bf16x8*>(qkvl + kb + kstep);
        stg[4] = *reinterpret_cast<const bf16x8*>(vth + vb);
        stg[5] = *reinterpret_cast<const bf16x8*>(vth + vb + 32*T_);
        stg[6] = *reinterpret_cast<const bf16x8*>(vtl + vb);
        stg[7] = *reinterpret_cast<const bf16x8*>(vtl + vb + 32*T_);
        *reinterpret_cast<bf16x8*>(&Khi[d0])        = stg[0];
        *reinterpret_cast<bf16x8*>(&Khi[d0 + 2048]) = stg[1];
        *reinterpret_cast<bf16x8*>(&Klo[d0])        = stg[2];
        *reinterpret_cast<bf16x8*>(&Klo[d0 + 2048]) = stg[3];
        *reinterpret_cast<bf16x8*>(&Vhi[d0])        = stg[4];
        *reinterpret_cast<bf16x8*>(&Vhi[d0 + 2048]) = stg[5];
        *reinterpret_cast<bf16x8*>(&Vlo[d0])        = stg[6];
        *reinterpret_cast<bf16x8*>(&Vlo[d0 + 2048]) = stg[7];
    }
    __syncthreads();

    f32x4 oa[4] = {};
    float mrow[4] = {-__builtin_inff(), -__builtin_inff(), -__builtin_inff(), -__builtin_inff()};
    float lrow[4] = {};

    for (int kt = 0; kt <= qt; ++kt) {
        // ---- QK^T: S[16 q][64 kv], bf16x3, K frags from LDS ----
        f32x4 sa[4] = {};
        #pragma unroll
        for (int ks = 0; ks < 2; ++ks) {
            bf16x8 kh[4], kl[4];
            #pragma unroll
            for (int nf = 0; nf < 4; ++nf) {
                const int row = 16*nf + r;
                const unsigned boff = (unsigned)(row * 128)
                    + (((unsigned)(ks*64 + g*16)) ^ ((unsigned)((row & 7) << 4)));
                kh[nf] = *reinterpret_cast<const bf16x8*>((const char*)Khi + boff);
                kl[nf] = *reinterpret_cast<const bf16x8*>((const char*)Klo + boff);
            }
            #pragma unroll
            for (int nf = 0; nf < 4; ++nf) {
                sa[nf] = __builtin_amdgcn_mfma_f32_16x16x32_bf16(qh[ks], kh[nf], sa[nf], 0, 0, 0);
                sa[nf] = __builtin_amdgcn_mfma_f32_16x16x32_bf16(ql[ks], kh[nf], sa[nf], 0, 0, 0);
                sa[nf] = __builtin_amdgcn_mfma_f32_16x16x32_bf16(qh[ks], kl[nf], sa[nf], 0, 0, 0);
            }
        }

        // ---- issue next tile's staging loads into registers (T14 split) ----
        if (kt < qt) {
            const size_t kb = ksrc0 + (size_t)((kt+1)*64) * (3*M_);
            const size_t vb = vsrc0 + (size_t)((kt+1)*64);
            const size_t kstep = (size_t)32 * (3*M_);
            stg[0] = *reinterpret_cast<const bf16x8*>(qkvh + kb);
            stg[1] = *reinterpret_cast<const bf16x8*>(qkvh + kb + kstep);
            stg[2] = *reinterpret_cast<const bf16x8*>(qkvl + kb);
            stg[3] = *reinterpret_cast<const bf16x8*>(qkvl + kb + kstep);
            stg[4] = *reinterpret_cast<const bf16x8*>(vth + vb);
            stg[5] = *reinterpret_cast<const bf16x8*>(vth + vb + 32*T_);
            stg[6] = *reinterpret_cast<const bf16x8*>(vtl + vb);
            stg[7] = *reinterpret_cast<const bf16x8*>(vtl + vb + 32*T_);
        }

        // ---- scale + causal mask ----
        float sv[4][4];
        #pragma unroll
        for (int nf = 0; nf < 4; ++nf)
            #pragma unroll
            for (int i = 0; i < 4; ++i)
                sv[nf][i] = sa[nf][i] * 0.125f;
        if (kt == qt) {
            #pragma unroll
            for (int nf = 0; nf < 4; ++nf) {
                const int kvg = kt*64 + 16*nf + r;
                #pragma unroll
                for (int i = 0; i < 4; ++i) {
                    const int qg = q0 + 16*w + 4*g + i;
                    if (kvg > qg) sv[nf][i] = -3.0e38f;
                }
            }
        }

        // ---- online softmax (native exp, verified r9) ----
        float tmax[4];
        #pragma unroll
        for (int i = 0; i < 4; ++i)
            tmax[i] = fmaxf(fmaxf(sv[0][i], sv[1][i]), fmaxf(sv[2][i], sv[3][i]));
        #pragma unroll
        for (int off = 1; off < 16; off <<= 1)
            #pragma unroll
            for (int i = 0; i < 4; ++i)
                tmax[i] = fmaxf(tmax[i], __shfl_xor(tmax[i], off));
        float mnew[4], corr[4];
        #pragma unroll
        for (int i = 0; i < 4; ++i) {
            mnew[i] = fmaxf(mrow[i], tmax[i]);
            corr[i] = __expf(mrow[i] - mnew[i]);
        }
        float p[4][4];
        float rsum[4] = {};
        #pragma unroll
        for (int nf = 0; nf < 4; ++nf)
            #pragma unroll
            for (int i = 0; i < 4; ++i) {
                p[nf][i] = __expf(sv[nf][i] - mnew[i]);
                rsum[i] += p[nf][i];
            }
        #pragma unroll
        for (int off = 1; off < 16; off <<= 1)
            #pragma unroll
            for (int i = 0; i < 4; ++i)
                rsum[i] += __shfl_xor(rsum[i], off);
        #pragma unroll
        for (int i = 0; i < 4; ++i) {
            lrow[i] = lrow[i] * corr[i] + rsum[i];
            mrow[i] = mnew[i];
        }
        #pragma unroll
        for (int df = 0; df < 4; ++df)
            #pragma unroll
            for (int i = 0; i < 4; ++i)
                oa[df][i] *= corr[i];

        // ---- write P (per-wave [16 q][72 kv], hi/lo) ----
        #pragma unroll
        for (int nf = 0; nf < 4; ++nf) {
            const int kv = 16*nf + r;
            #pragma unroll
            for (int i = 0; i < 4; ++i) {
                const ushort_t phb = f2bf(p[nf][i]);
                Ph[(w*16 + 4*g + i) * 72 + kv] = phb;
                Pl[(w*16 + 4*g + i) * 72 + kv] = f2bf(p[nf][i] - bf2f(phb));
            }
        }
        lgkm0();   // P writes visible to this wave's reads (per-wave buffer)

        // ---- PV: O += P·V, bf16x3, V frags from LDS ----
        #pragma unroll
        for (int ks = 0; ks < 2; ++ks) {
            const bf16x8 ph = *reinterpret_cast<const bf16x8*>(&Ph[(w*16 + r) * 72 + 32*ks + 8*g]);
            const bf16x8 pl = *reinterpret_cast<const bf16x8*>(&Pl[(w*16 + r) * 72 + 32*ks + 8*g]);
            #pragma unroll
            for (int df = 0; df < 4; ++df) {
                const int vrow = 16*df + r;
                const unsigned voff = (unsigned)(vrow * 128)
                    + (((unsigned)(ks*64 + g*16)) ^ ((unsigned)((vrow & 7) << 4)));
                const bf16x8 vhf = *reinterpret_cast<const bf16x8*>((const char*)Vhi + voff);
                const bf16x8 vlf = *reinterpret_cast<const bf16x8*>((const char*)Vlo + voff);
                oa[df] = __builtin_amdgcn_mfma_f32_16x16x32_bf16(ph, vhf, oa[df], 0, 0, 0);
                oa[df] = __builtin_amdgcn_mfma_f32_16x16x32_bf16(pl, vhf, oa[df], 0, 0, 0);
                oa[df] = __builtin_amdgcn_mfma_f32_16x16x32_bf16(ph, vlf, oa[df], 0, 0, 0);
            }
        }

        // ---- commit staged registers to LDS for next tile ----
        if (kt < qt) {
            __syncthreads();                       // all reads of tile kt done
            *reinterpret_cast<bf16x8*>(&Khi[d0])        = stg[0];
            *reinterpret_cast<bf16x8*>(&Khi[d0 + 2048]) = stg[1];
            *reinterpret_cast<bf16x8*>(&Klo[d0])        = stg[2];
            *reinterpret_cast<bf16x8*>(&Klo[d0 + 2048]) = stg[3];
            *reinterpret_cast<bf16x8*>(&Vhi[d0])        = stg[4];
            *reinterpret_cast<bf16x8*>(&Vhi[d0 + 2048]) = stg[5];
            *reinterpret_cast<bf16x8*>(&Vlo[d0])        = stg[6];
            *reinterpret_cast<bf16x8*>(&Vlo[d0 + 2048]) = stg[7];
            __syncthreads();                       // writes visible
        }
    }

    // ---- epilogue: hi/lo split of O / l ----
    #pragma unroll
    for (int i = 0; i < 4; ++i) {
        const float inv = 1.0f / lrow[i];
        const size_t row = (rowbase + q0 + 16*w + 4*g + i) * (size_t)M_ + hoff;
        #pragma unroll
        for (int df = 0; df < 4; ++df) {
            const float v = oa[df][i] * inv;
            const ushort_t hb = f2bf(v);
            ohi[row + 16*df + r] = hb;
            olo[row + 16*df + r] = f2bf(v - bf2f(hb));
        }
    }
}

// ---------------------------------------------------------------------------
// Router + deepspeed dispatch bookkeeping (exact, f32).
// ---------------------------------------------------------------------------
__global__ __launch_bounds__(256) void gate_kernel(const float* __restrict__ h2,
                                                   const float* __restrict__ wg,
                                                   int* __restrict__ gidx,
                                                   float* __restrict__ gtop)
{
    const int s = blockIdx.x;
    const int e = threadIdx.x >> 5;
    const int l = threadIdx.x & 31;
    const float* row = h2 + (size_t)s * M_;
    float acc = 0.0f;
    for (int m = l; m < M_; m += 32) acc = fmaf(row[m], wg[m * E_ + e], acc);
    #pragma unroll
    for (int off = 16; off > 0; off >>= 1) acc += __shfl_down(acc, off, 32);
    __shared__ float lg[E_];
    if (l == 0) lg[e] = acc;
    __syncthreads();
    if (threadIdx.x == 0) {
        float mx = lg[0]; int bi = 0;
        #pragma unroll
        for (int i = 1; i < E_; ++i) { if (lg[i] > mx) { mx = lg[i]; bi = i; } }
        float den = 0.0f;
        #pragma unroll
        for (int i = 0; i < E_; ++i) den += expf(lg[i] - mx);
        gidx[s] = bi;
        gtop[s] = 1.0f / den;
    }
}

__global__ __launch_bounds__(1024) void scan_kernel(const int* __restrict__ gidx,
                                                    const float* __restrict__ gtop,
                                                    float* __restrict__ gate_val,
                                                    int* __restrict__ token_at)
{
    __shared__ int hist[1024][E_];
    const int tid = threadIdx.x;
    for (int i = tid; i < E_ * C_; i += 1024) token_at[i] = -1;
    int my[8];
    #pragma unroll
    for (int t = 0; t < 8; ++t) my[t] = gidx[tid * 8 + t];
    #pragma unroll
    for (int e = 0; e < E_; ++e) {
        int c = 0;
        #pragma unroll
        for (int t = 0; t < 8; ++t) c += (my[t] == e) ? 1 : 0;
        hist[tid][e] = c;
    }
    __syncthreads();
    if (tid < E_) {
        int run = 0;
        for (int t = 0; t < 1024; ++t) {
            const int v = hist[t][tid];
            hist[t][tid] = run;
            run += v;
        }
    }
    __syncthreads();
    #pragma unroll
    for (int t = 0; t < 8; ++t) {
        const int s = tid * 8 + t;
        const int e = my[t];
        const int p = hist[tid][e];
        hist[tid][e] = p + 1;
        const bool keep = (p < C_);
        gate_val[s] = keep ? gtop[s] : 0.0f;
        if (keep) token_at[e * C_ + p] = s;
    }
}

__global__ __launch_bounds__(256) void dispatch_bf16_kernel(const float* __restrict__ h2,
                                                            const int* __restrict__ token_at,
                                                            ushort_t* __restrict__ disp)
{
    const int ec = blockIdx.x;
    const int s = token_at[ec];
    ushort4* dst = reinterpret_cast<ushort4*>(disp + (size_t)ec * M_);
    if (s >= 0) {
        const float4 v = reinterpret_cast<const float4*>(h2 + (size_t)s * M_)[threadIdx.x];
        dst[threadIdx.x] = make_ushort4(f2bf(v.x), f2bf(v.y), f2bf(v.z), f2bf(v.w));
    } else {
        dst[threadIdx.x] = make_ushort4(0, 0, 0, 0);
    }
}

// Transpose+convert: in[e][R][Cc] f32 -> out[e][Cc][R] bf16.
__global__ __launch_bounds__(256) void transpose_bf16_kernel(const float* __restrict__ in,
                                                             ushort_t* __restrict__ outp,
                                                             int R, int Cc)
{
    __shared__ float tile[32][33];
    const int e = blockIdx.z;
    in   += (size_t)e * R * Cc;
    outp += (size_t)e * R * Cc;
    const int tx = threadIdx.x & 31, ty0 = threadIdx.x >> 5;
    const int c0 = blockIdx.x * 32, r0 = blockIdx.y * 32;
    #pragma unroll
    for (int i = 0; i < 4; ++i)
        tile[ty0 + 8*i][tx] = in[(size_t)(r0 + ty0 + 8*i) * Cc + c0 + tx];
    __syncthreads();
    #pragma unroll
    for (int i = 0; i < 4; ++i)
        outp[(size_t)(c0 + ty0 + 8*i) * R + r0 + tx] = f2bf(tile[tx][ty0 + 8*i]);
}

// ---------------------------------------------------------------------------
// bf16 MFMA GEMM (MoE FFN, post-router) — unchanged, verified.
// ---------------------------------------------------------------------------
template<int EPI>
__global__ __launch_bounds__(256) void gemm_mfma(
    const ushort_t* __restrict__ A, const ushort_t* __restrict__ Bt,
    const float* __restrict__ bias,
    const int* __restrict__ token_at, const float* __restrict__ gate_val,
    void* __restrict__ Cout, int N, int K,
    long strA, long strB, long strBias, long strC)
{
    const int e = blockIdx.z;
    A    += (size_t)e * (size_t)strA;
    Bt   += (size_t)e * (size_t)strB;
    bias += (size_t)e * (size_t)strBias;

    __shared__ ushort_t As[128 * 32];
    __shared__ ushort_t Bs[128 * 32];

    const int t  = threadIdx.x;
    const int l  = t & 63;
    const int wv = t >> 6;
    const int wm = (wv & 1) * 64, wn = (wv >> 1) * 64;
    const int fr = l & 15, fk = (l >> 4) * 8;
    const int m0 = blockIdx.y * 128, n0 = blockIdx.x * 128;

    const ushort_t* gA = A + (size_t)(m0 + (t >> 2)) * K + (t & 3) * 8;
    const ushort_t* gB = Bt + (size_t)(n0 + (t >> 2)) * K + (t & 3) * 8;
    ushort_t* lA = As + wv * 512;
    ushort_t* lB = Bs + wv * 512;

    f32x4 acc[4][4] = {};

    for (int k0 = 0; k0 < K; k0 += 32) {
        __syncthreads();
        gload_lds16(gA + k0, lA);
        gload_lds16(gA + k0 + (size_t)64 * K, lA + 2048);
        gload_lds16(gB + k0, lB);
        gload_lds16(gB + k0 + (size_t)64 * K, lB + 2048);
        __syncthreads();
        bf16x8 af[4], bfr[4];
        #pragma unroll
        for (int i = 0; i < 4; ++i)
            af[i] = *reinterpret_cast<const bf16x8*>(&As[(wm + i*16 + fr) * 32 + fk]);
        #pragma unroll
        for (int i = 0; i < 4; ++i)
            bfr[i] = *reinterpret_cast<const bf16x8*>(&Bs[(wn + i*16 + fr) * 32 + fk]);
        #pragma unroll
        for (int mi = 0; mi < 4; ++mi) {
            #pragma unroll
            for (int ni = 0; ni < 4; ++ni)
                acc[mi][ni] = __builtin_amdgcn_mfma_f32_16x16x32_bf16(
                    af[mi], bfr[ni], acc[mi][ni], 0, 0, 0);
        }
    }

    const int l4 = (l >> 4) * 4;
    if (EPI == 0) {
        ushort_t* Cc = (ushort_t*)Cout + (size_t)e * (size_t)strC;
        #pragma unroll
        for (int ni = 0; ni < 4; ++ni) {
            const int cl = n0 + wn + ni*16 + fr;
            const float bb = bias[cl];
            #pragma unroll
            for (int mi = 0; mi < 4; ++mi) {
                #pragma unroll
                for (int i = 0; i < 4; ++i) {
                    const int rr = m0 + wm + mi*16 + l4 + i;
                    Cc[(size_t)rr * N + cl] = f2bf(gelu_exact(acc[mi][ni][i] + bb));
                }
            }
        }
    } else {
        float* Co = (float*)Cout;
        const int* ta = token_at + e * C_;
        #pragma unroll
        for (int mi = 0; mi < 4; ++mi) {
            #pragma unroll
            for (int i = 0; i < 4; ++i) {
                const int rr = m0 + wm + mi*16 + l4 + i;
                const int s = ta[rr];
                if (s >= 0) {
                    const float gvl = gate_val[s];
                    #pragma unroll
                    for (int ni = 0; ni < 4; ++ni) {
                        const int cl = n0 + wn + ni*16 + fr;
                        Co[(size_t)s * N + cl] += gvl * (acc[mi][ni][i] + bias[cl]);
                    }
                }
            }
        }
    }
}

// ---------------------------------------------------------------------------
extern "C" void kernel_launch(void* const* d_in, const int* in_sizes, int n_in,
                              void* d_out, int out_size, void* d_ws, size_t ws_size,
                              hipStream_t stream)
{
    const float* x    = (const float*)d_in[0];
    const float* ln1g = (const float*)d_in[1];
    const float* ln1b = (const float*)d_in[2];
    const float* Wqkv = (const float*)d_in[3];
    const float* bqkv = (const float*)d_in[4];
    const float* Wout = (const float*)d_in[5];
    const float* bout = (const float*)d_in[6];
    const float* ln2g = (const float*)d_in[7];
    const float* ln2b = (const float*)d_in[8];
    const float* wg   = (const float*)d_in[9];
    const float* w1   = (const float*)d_in[10];
    const float* b1   = (const float*)d_in[11];
    const float* w2   = (const float*)d_in[12];
    const float* b2   = (const float*)d_in[13];
    float* out = (float*)d_out;

    // Workspace (MiB offsets), lifetime-scheduled. Peak ~196 MiB.
    char* ws = (char*)d_ws;
    ushort_t* ahi   = (ushort_t*)ws;
    ushort_t* alo   = (ushort_t*)(ws + ((size_t)16  << 20));
    float*    buf_h = (float*)ws;
    ushort_t* qkvh  = (ushort_t*)(ws + ((size_t)32  << 20));
    ushort_t* qkvl  = (ushort_t*)(ws + ((size_t)80  << 20));
    ushort_t* vth   = (ushort_t*)(ws + ((size_t)128 << 20));
    ushort_t* vtl   = (ushort_t*)(ws + ((size_t)144 << 20));
    ushort_t* ohi   = (ushort_t*)(ws + ((size_t)160 << 20));
    ushort_t* olo   = (ushort_t*)(ws + ((size_t)176 << 20));
    ushort_t* wqh   = (ushort_t*)(ws + ((size_t)128 << 20));   // ph1 only
    ushort_t* wql   = (ushort_t*)(ws + ((size_t)134 << 20));   // ph1 only
    ushort_t* woh   = (ushort_t*)(ws + ((size_t)192 << 20));
    ushort_t* wol   = (ushort_t*)(ws + ((size_t)194 << 20));
    ushort_t* w1t   = (ushort_t*)(ws + ((size_t)32  << 20));
    ushort_t* w2t   = (ushort_t*)(ws + ((size_t)32  << 20));
    ushort_t* dispb = (ushort_t*)(ws + ((size_t)96  << 20));
    ushort_t* h1b   = (ushort_t*)(ws + ((size_t)112 << 20));
    float*    buf_gtop = (float*)(ws + ((size_t)196 << 20));
    float*    buf_gv   = buf_gtop + S_;
    int*      buf_idx  = (int*)(buf_gv + S_);
    int*      buf_ta   = buf_idx + S_;

    // --- pre-router path (f32-grade via bf16x3 MFMA) ---
    split_kernel<<<(3*M_*M_/4 + 255)/256, 256, 0, stream>>>(Wqkv, wqh, wql, 3*M_*M_/4);
    split_kernel<<<(M_*M_/4 + 255)/256, 256, 0, stream>>>(Wout, woh, wol, M_*M_/4);
    ln_split_kernel<<<S_, 256, 0, stream>>>(x, ln1g, ln1b, ahi, alo);
    gemm_bf16x3<2><<<dim3(3*M_/128, S_/128, 1), 256, 0, stream>>>(
        ahi, alo, wqh, wql, bqkv, nullptr, qkvh, qkvl, 3*M_, M_);
    vtrans_kernel<<<dim3(T_/64, H_, B_), 256, 0, stream>>>(qkvh, qkvl, vth, vtl);
    attn_mfma_kernel<<<dim3(T_/64, H_, B_), 256, 0, stream>>>(qkvh, qkvl, vth, vtl, ohi, olo);
    gemm_bf16x3<1><<<dim3(M_/128, S_/128, 1), 256, 0, stream>>>(
        ohi, olo, woh, wol, bout, x, out, nullptr, M_, M_);

    // --- router (exact f32) ---
    ln_kernel<<<S_, 256, 0, stream>>>(out, ln2g, ln2b, buf_h);
    gate_kernel<<<S_, 256, 0, stream>>>(buf_h, wg, buf_idx, buf_gtop);
    scan_kernel<<<1, 1024, 0, stream>>>(buf_idx, buf_gtop, buf_gv, buf_ta);
    dispatch_bf16_kernel<<<E_*C_, 256, 0, stream>>>(buf_h, buf_ta, dispb);

    // --- MoE FFN (bf16 MFMA, post-router) ---
    transpose_bf16_kernel<<<dim3(F_/32, M_/32, E_), 256, 0, stream>>>(w1, w1t, M_, F_);
    gemm_mfma<0><<<dim3(F_/128, C_/128, E_), 256, 0, stream>>>(
        dispb, w1t, b1, nullptr, nullptr, h1b, F_, M_,
        (long)C_*M_, (long)F_*M_, (long)F_, (long)C_*F_);
    transpose_bf16_kernel<<<dim3(M_/32, F_/32, E_), 256, 0, stream>>>(w2, w2t, F_, M_);
    gemm_mfma<1><<<dim3(M_/128, C_/128, E_), 256, 0, stream>>>(
        h1b, w2t, b2, buf_ta, buf_gv, out, M_, F_,
        (long)C_*F_, (long)M_*F_, (long)M_, 0);
}

// Round 11
// 1017.319 us; speedup vs baseline: 1.6886x; 1.1279x over previous
//
#include <hip/hip_runtime.h>
#include <hip/hip_bf16.h>
#include <math.h>

#define B_ 4
#define T_ 2048
#define M_ 1024
#define H_ 16
#define E_ 8
#define S_ (B_*T_)      // 8192
#define C_ (S_/E_)      // 1024
#define D_ (M_/H_)      // 64
#define F_ (4*M_)       // 4096

typedef unsigned short ushort_t;
typedef __attribute__((ext_vector_type(8))) short bf16x8;
typedef __attribute__((ext_vector_type(4))) float f32x4;

__device__ __forceinline__ float gelu_exact(float x) {
    return 0.5f * x * (1.0f + erff(x * 0.70710678118654752440f));
}

__device__ __forceinline__ unsigned short f2bf(float f) {
    unsigned int u = __float_as_uint(f);
    u = (u + 0x7FFFu + ((u >> 16) & 1u)) >> 16;   // RNE
    return (unsigned short)u;
}

__device__ __forceinline__ float bf2f(unsigned short h) {
    return __uint_as_float(((unsigned)h) << 16);
}

__device__ __forceinline__ void gload_lds16(const void* g, void* l) {
    __builtin_amdgcn_global_load_lds(
        (const __attribute__((address_space(1))) unsigned int*)g,
        (__attribute__((address_space(3))) unsigned int*)l,
        16, 0, 0);
}

__device__ __forceinline__ void lgkm0() {
    asm volatile("s_waitcnt lgkmcnt(0)" ::: "memory");
}

// ---------------------------------------------------------------------------
// LayerNorm (f32 out).
// ---------------------------------------------------------------------------
__global__ __launch_bounds__(256) void ln_kernel(const float* __restrict__ x,
                                                 const float* __restrict__ g,
                                                 const float* __restrict__ bta,
                                                 float* __restrict__ out)
{
    const int row = blockIdx.x;
    const int tid = threadIdx.x;
    const float4 v = reinterpret_cast<const float4*>(x + (size_t)row * M_)[tid];
    float s = v.x + v.y + v.z + v.w;
    __shared__ float red[4];
    #pragma unroll
    for (int off = 32; off > 0; off >>= 1) s += __shfl_down(s, off);
    if ((tid & 63) == 0) red[tid >> 6] = s;
    __syncthreads();
    const float mu = (red[0] + red[1] + red[2] + red[3]) * (1.0f / (float)M_);
    __syncthreads();
    float4 d;
    d.x = v.x - mu; d.y = v.y - mu; d.z = v.z - mu; d.w = v.w - mu;
    float q = d.x*d.x + d.y*d.y + d.z*d.z + d.w*d.w;
    #pragma unroll
    for (int off = 32; off > 0; off >>= 1) q += __shfl_down(q, off);
    if ((tid & 63) == 0) red[tid >> 6] = q;
    __syncthreads();
    const float var  = (red[0] + red[1] + red[2] + red[3]) * (1.0f / (float)M_);
    const float rstd = 1.0f / sqrtf(var + 1e-5f);
    const float4 gv = reinterpret_cast<const float4*>(g)[tid];
    const float4 bv = reinterpret_cast<const float4*>(bta)[tid];
    float4 o;
    o.x = d.x * rstd * gv.x + bv.x;
    o.y = d.y * rstd * gv.y + bv.y;
    o.z = d.z * rstd * gv.z + bv.z;
    o.w = d.w * rstd * gv.w + bv.w;
    reinterpret_cast<float4*>(out + (size_t)row * M_)[tid] = o;
}

// LayerNorm fused with hi/lo bf16 split output.
__global__ __launch_bounds__(256) void ln_split_kernel(const float* __restrict__ x,
                                                       const float* __restrict__ g,
                                                       const float* __restrict__ bta,
                                                       ushort_t* __restrict__ hi,
                                                       ushort_t* __restrict__ lo)
{
    const int row = blockIdx.x;
    const int tid = threadIdx.x;
    const float4 v = reinterpret_cast<const float4*>(x + (size_t)row * M_)[tid];
    float s = v.x + v.y + v.z + v.w;
    __shared__ float red[4];
    #pragma unroll
    for (int off = 32; off > 0; off >>= 1) s += __shfl_down(s, off);
    if ((tid & 63) == 0) red[tid >> 6] = s;
    __syncthreads();
    const float mu = (red[0] + red[1] + red[2] + red[3]) * (1.0f / (float)M_);
    __syncthreads();
    float4 d;
    d.x = v.x - mu; d.y = v.y - mu; d.z = v.z - mu; d.w = v.w - mu;
    float q = d.x*d.x + d.y*d.y + d.z*d.z + d.w*d.w;
    #pragma unroll
    for (int off = 32; off > 0; off >>= 1) q += __shfl_down(q, off);
    if ((tid & 63) == 0) red[tid >> 6] = q;
    __syncthreads();
    const float var  = (red[0] + red[1] + red[2] + red[3]) * (1.0f / (float)M_);
    const float rstd = 1.0f / sqrtf(var + 1e-5f);
    const float4 gv = reinterpret_cast<const float4*>(g)[tid];
    const float4 bv = reinterpret_cast<const float4*>(bta)[tid];
    float o[4];
    o[0] = d.x * rstd * gv.x + bv.x;
    o[1] = d.y * rstd * gv.y + bv.y;
    o[2] = d.z * rstd * gv.z + bv.z;
    o[3] = d.w * rstd * gv.w + bv.w;
    ushort4 hh, ll;
    hh.x = f2bf(o[0]); ll.x = f2bf(o[0] - bf2f(hh.x));
    hh.y = f2bf(o[1]); ll.y = f2bf(o[1] - bf2f(hh.y));
    hh.z = f2bf(o[2]); ll.z = f2bf(o[2] - bf2f(hh.z));
    hh.w = f2bf(o[3]); ll.w = f2bf(o[3] - bf2f(hh.w));
    reinterpret_cast<ushort4*>(hi + (size_t)row * M_)[tid] = hh;
    reinterpret_cast<ushort4*>(lo + (size_t)row * M_)[tid] = ll;
}

// Elementwise f32 -> hi/lo bf16 split (weights).
__global__ __launch_bounds__(256) void split_kernel(const float* __restrict__ in,
                                                    ushort_t* __restrict__ hi,
                                                    ushort_t* __restrict__ lo,
                                                    int n4)
{
    const int i = blockIdx.x * 256 + threadIdx.x;
    if (i >= n4) return;
    const float4 v = reinterpret_cast<const float4*>(in)[i];
    ushort4 hh, ll;
    hh.x = f2bf(v.x); ll.x = f2bf(v.x - bf2f(hh.x));
    hh.y = f2bf(v.y); ll.y = f2bf(v.y - bf2f(hh.y));
    hh.z = f2bf(v.z); ll.z = f2bf(v.z - bf2f(hh.z));
    hh.w = f2bf(v.w); ll.w = f2bf(v.w - bf2f(hh.w));
    reinterpret_cast<ushort4*>(hi)[i] = hh;
    reinterpret_cast<ushort4*>(lo)[i] = ll;
}

// V^T pre-transpose: qkv hi/lo [s][3M] (V slice) -> vt hi/lo [(b*H+h)*64+d][T].
__global__ __launch_bounds__(256) void vtrans_kernel(const ushort_t* __restrict__ qkvh,
                                                     const ushort_t* __restrict__ qkvl,
                                                     ushort_t* __restrict__ vth,
                                                     ushort_t* __restrict__ vtl)
{
    __shared__ ushort_t tile[64][72];
    const int t0 = blockIdx.x * 64, h = blockIdx.y, b = blockIdx.z;
    const int tid = threadIdx.x;
    const int tr = tid & 63, dc = (tid >> 6) * 16;
    const size_t src = ((size_t)(b*T_ + t0 + tr)) * (3*M_) + 2*M_ + h*64 + dc;
    const int dr = tid & 63, tc = (tid >> 6) * 16;
    const size_t dst = ((size_t)((b*H_ + h)*64 + dr)) * T_ + t0 + tc;

    #pragma unroll
    for (int pass = 0; pass < 2; ++pass) {
        const ushort_t* in = pass ? qkvl : qkvh;
        ushort_t* outp     = pass ? vtl  : vth;
        *reinterpret_cast<bf16x8*>(&tile[tr][dc])     = *reinterpret_cast<const bf16x8*>(in + src);
        *reinterpret_cast<bf16x8*>(&tile[tr][dc + 8]) = *reinterpret_cast<const bf16x8*>(in + src + 8);
        __syncthreads();
        bf16x8 o0, o1;
        #pragma unroll
        for (int j = 0; j < 8; ++j) {
            o0[j] = (short)tile[tc + j][dr];
            o1[j] = (short)tile[tc + 8 + j][dr];
        }
        *reinterpret_cast<bf16x8*>(outp + dst)     = o0;
        *reinterpret_cast<bf16x8*>(outp + dst + 8) = o1;
        __syncthreads();
    }
}

// ---------------------------------------------------------------------------
// bf16x3 MFMA GEMM (f32-grade, pre-router). m97 structure, 4 LDS buffers.
// EPI 1: f32 out = acc + bias + res.   EPI 2: hi/lo bf16 out = split(acc+bias).
// ---------------------------------------------------------------------------
template<int EPI>
__global__ __launch_bounds__(256) void gemm_bf16x3(
    const ushort_t* __restrict__ Ahi, const ushort_t* __restrict__ Alo,
    const ushort_t* __restrict__ Bhi, const ushort_t* __restrict__ Blo,
    const float* __restrict__ bias, const float* __restrict__ res,
    void* __restrict__ C0, ushort_t* __restrict__ C1, int N, int K)
{
    __shared__ ushort_t AsH[128*32], AsL[128*32];
    __shared__ ushort_t BsH[128*32], BsL[128*32];

    const int t  = threadIdx.x;
    const int l  = t & 63;
    const int wv = t >> 6;
    const int wm = (wv & 1) * 64, wn = (wv >> 1) * 64;
    const int fr = l & 15, fk = (l >> 4) * 8;
    const int m0 = blockIdx.y * 128, n0 = blockIdx.x * 128;

    const size_t arow = (size_t)(m0 + (t >> 2)) * K + (t & 3) * 8;
    const size_t brow = (size_t)(n0 + (t >> 2)) * K + (t & 3) * 8;
    ushort_t* lAH = AsH + wv * 512;
    ushort_t* lAL = AsL + wv * 512;
    ushort_t* lBH = BsH + wv * 512;
    ushort_t* lBL = BsL + wv * 512;

    f32x4 acc[4][4] = {};

    for (int k0 = 0; k0 < K; k0 += 32) {
        __syncthreads();
        gload_lds16(Ahi + arow + k0, lAH);
        gload_lds16(Ahi + arow + k0 + (size_t)64 * K, lAH + 2048);
        gload_lds16(Alo + arow + k0, lAL);
        gload_lds16(Alo + arow + k0 + (size_t)64 * K, lAL + 2048);
        gload_lds16(Bhi + brow + k0, lBH);
        gload_lds16(Bhi + brow + k0 + (size_t)64 * K, lBH + 2048);
        gload_lds16(Blo + brow + k0, lBL);
        gload_lds16(Blo + brow + k0 + (size_t)64 * K, lBL + 2048);
        __syncthreads();
        bf16x8 ah[4], al[4], bh[4], bl[4];
        #pragma unroll
        for (int i = 0; i < 4; ++i) {
            ah[i] = *reinterpret_cast<const bf16x8*>(&AsH[(wm + i*16 + fr) * 32 + fk]);
            al[i] = *reinterpret_cast<const bf16x8*>(&AsL[(wm + i*16 + fr) * 32 + fk]);
            bh[i] = *reinterpret_cast<const bf16x8*>(&BsH[(wn + i*16 + fr) * 32 + fk]);
            bl[i] = *reinterpret_cast<const bf16x8*>(&BsL[(wn + i*16 + fr) * 32 + fk]);
        }
        #pragma unroll
        for (int mi = 0; mi < 4; ++mi) {
            #pragma unroll
            for (int ni = 0; ni < 4; ++ni) {
                acc[mi][ni] = __builtin_amdgcn_mfma_f32_16x16x32_bf16(ah[mi], bh[ni], acc[mi][ni], 0, 0, 0);
                acc[mi][ni] = __builtin_amdgcn_mfma_f32_16x16x32_bf16(al[mi], bh[ni], acc[mi][ni], 0, 0, 0);
                acc[mi][ni] = __builtin_amdgcn_mfma_f32_16x16x32_bf16(ah[mi], bl[ni], acc[mi][ni], 0, 0, 0);
            }
        }
    }

    // C/D: col = lane&15, row = (lane>>4)*4 + reg
    const int l4 = (l >> 4) * 4;
    #pragma unroll
    for (int mi = 0; mi < 4; ++mi) {
        #pragma unroll
        for (int i = 0; i < 4; ++i) {
            const int row = m0 + wm + mi*16 + l4 + i;
            #pragma unroll
            for (int ni = 0; ni < 4; ++ni) {
                const int col = n0 + wn + ni*16 + fr;
                float v = acc[mi][ni][i] + bias[col];
                if (EPI == 1) {
                    v += res[(size_t)row * N + col];
                    ((float*)C0)[(size_t)row * N + col] = v;
                } else {
                    const ushort_t hb = f2bf(v);
                    ((ushort_t*)C0)[(size_t)row * N + col] = hb;
                    C1[(size_t)row * N + col] = f2bf(v - bf2f(hb));
                }
            }
        }
    }
}

// ---------------------------------------------------------------------------
// bf16x3 MFMA flash attention — PERSISTENT form. 768 blocks (3/CU, all
// co-resident); each block processes 2-3 (qt,h,b) items via snake-balanced
// static schedule (j, 1535-j, 1536+j over qt-descending rank). Per-item body
// is bit-identical to round 10 (LDS staging + T14 register prefetch).
// ---------------------------------------------------------------------------
__global__ __launch_bounds__(256) void attn_mfma_kernel(
    const ushort_t* __restrict__ qkvh, const ushort_t* __restrict__ qkvl,
    const ushort_t* __restrict__ vth,  const ushort_t* __restrict__ vtl,
    ushort_t* __restrict__ ohi, ushort_t* __restrict__ olo)
{
    const int j = (int)blockIdx.x;                 // 0..767
    const int t = threadIdx.x;
    const int w = t >> 6, l = t & 63;
    const int r = l & 15, g = l >> 4;

    __shared__ ushort_t Khi[64*64], Klo[64*64];    // [kv][64] swizzled
    __shared__ ushort_t Vhi[64*64], Vlo[64*64];    // V^T [d][64 kv] swizzled
    __shared__ ushort_t Ph[4*16*72], Pl[4*16*72];

    int items[3];
    int ni = 0;
    items[ni++] = j;
    items[ni++] = 1535 - j;
    if (1536 + j < 2048) items[ni++] = 1536 + j;

    // staging lane geometry (item-independent)
    const int srow = w*8 + (l >> 3);
    const int scol = ((l & 7) ^ (l >> 3)) * 8;
    const int d0 = w * 512 + l * 8;                // ushort index; +2048 = rows+32

    for (int ii = 0; ii < ni; ++ii) {
        const int item = items[ii];
        const int qt  = 31 - (item >> 6);          // rank -> qt (descending)
        const int rem = item & 63;
        const int h = rem >> 2, b = rem & 3;
        const int q0 = qt * 64;
        const size_t rowbase = (size_t)b * T_;
        const int hoff = h * D_;

        // Q fragments (A-frag: row = l&15, k = 32ks + 8g + j)
        bf16x8 qh[2], ql[2];
        {
            const size_t qrow = (rowbase + q0 + 16*w + r) * (size_t)(3*M_) + hoff;
            #pragma unroll
            for (int ks = 0; ks < 2; ++ks) {
                qh[ks] = *reinterpret_cast<const bf16x8*>(qkvh + qrow + 32*ks + 8*g);
                ql[ks] = *reinterpret_cast<const bf16x8*>(qkvl + qrow + 32*ks + 8*g);
            }
        }

        const size_t ksrc0 = (rowbase + srow) * (size_t)(3*M_) + hoff + M_ + scol;
        const size_t vsrc0 = ((size_t)((b*H_ + h)*64 + srow)) * T_ + scol;

        bf16x8 stg[8];
        __syncthreads();   // previous item's LDS readers done
        // prologue: stage tile 0
        {
            const size_t kb = ksrc0, vb = vsrc0;
            const size_t kstep = (size_t)32 * (3*M_);
            stg[0] = *reinterpret_cast<const bf16x8*>(qkvh + kb);
            stg[1] = *reinterpret_cast<const bf16x8*>(qkvh + kb + kstep);
            stg[2] = *reinterpret_cast<const bf16x8*>(qkvl + kb);
            stg[3] = *reinterpret_cast<const bf16x8*>(qkvl + kb + kstep);
            stg[4] = *reinterpret_cast<const bf16x8*>(vth + vb);
            stg[5] = *reinterpret_cast<const bf16x8*>(vth + vb + 32*T_);
            stg[6] = *reinterpret_cast<const bf16x8*>(vtl + vb);
            stg[7] = *reinterpret_cast<const bf16x8*>(vtl + vb + 32*T_);
            *reinterpret_cast<bf16x8*>(&Khi[d0])        = stg[0];
            *reinterpret_cast<bf16x8*>(&Khi[d0 + 2048]) = stg[1];
            *reinterpret_cast<bf16x8*>(&Klo[d0])        = stg[2];
            *reinterpret_cast<bf16x8*>(&Klo[d0 + 2048]) = stg[3];
            *reinterpret_cast<bf16x8*>(&Vhi[d0])        = stg[4];
            *reinterpret_cast<bf16x8*>(&Vhi[d0 + 2048]) = stg[5];
            *reinterpret_cast<bf16x8*>(&Vlo[d0])        = stg[6];
            *reinterpret_cast<bf16x8*>(&Vlo[d0 + 2048]) = stg[7];
        }
        __syncthreads();

        f32x4 oa[4] = {};
        float mrow[4] = {-__builtin_inff(), -__builtin_inff(), -__builtin_inff(), -__builtin_inff()};
        float lrow[4] = {};

        for (int kt = 0; kt <= qt; ++kt) {
            // ---- QK^T: S[16 q][64 kv], bf16x3, K frags from LDS ----
            f32x4 sa[4] = {};
            #pragma unroll
            for (int ks = 0; ks < 2; ++ks) {
                bf16x8 kh[4], kl[4];
                #pragma unroll
                for (int nf = 0; nf < 4; ++nf) {
                    const int row = 16*nf + r;
                    const unsigned boff = (unsigned)(row * 128)
                        + (((unsigned)(ks*64 + g*16)) ^ ((unsigned)((row & 7) << 4)));
                    kh[nf] = *reinterpret_cast<const bf16x8*>((const char*)Khi + boff);
                    kl[nf] = *reinterpret_cast<const bf16x8*>((const char*)Klo + boff);
                }
                #pragma unroll
                for (int nf = 0; nf < 4; ++nf) {
                    sa[nf] = __builtin_amdgcn_mfma_f32_16x16x32_bf16(qh[ks], kh[nf], sa[nf], 0, 0, 0);
                    sa[nf] = __builtin_amdgcn_mfma_f32_16x16x32_bf16(ql[ks], kh[nf], sa[nf], 0, 0, 0);
                    sa[nf] = __builtin_amdgcn_mfma_f32_16x16x32_bf16(qh[ks], kl[nf], sa[nf], 0, 0, 0);
                }
            }

            // ---- issue next tile's staging loads into registers (T14) ----
            if (kt < qt) {
                const size_t kb = ksrc0 + (size_t)((kt+1)*64) * (3*M_);
                const size_t vb = vsrc0 + (size_t)((kt+1)*64);
                const size_t kstep = (size_t)32 * (3*M_);
                stg[0] = *reinterpret_cast<const bf16x8*>(qkvh + kb);
                stg[1] = *reinterpret_cast<const bf16x8*>(qkvh + kb + kstep);
                stg[2] = *reinterpret_cast<const bf16x8*>(qkvl + kb);
                stg[3] = *reinterpret_cast<const bf16x8*>(qkvl + kb + kstep);
                stg[4] = *reinterpret_cast<const bf16x8*>(vth + vb);
                stg[5] = *reinterpret_cast<const bf16x8*>(vth + vb + 32*T_);
                stg[6] = *reinterpret_cast<const bf16x8*>(vtl + vb);
                stg[7] = *reinterpret_cast<const bf16x8*>(vtl + vb + 32*T_);
            }

            // ---- scale + causal mask ----
            float sv[4][4];
            #pragma unroll
            for (int nf = 0; nf < 4; ++nf)
                #pragma unroll
                for (int i = 0; i < 4; ++i)
                    sv[nf][i] = sa[nf][i] * 0.125f;
            if (kt == qt) {
                #pragma unroll
                for (int nf = 0; nf < 4; ++nf) {
                    const int kvg = kt*64 + 16*nf + r;
                    #pragma unroll
                    for (int i = 0; i < 4; ++i) {
                        const int qg = q0 + 16*w + 4*g + i;
                        if (kvg > qg) sv[nf][i] = -3.0e38f;
                    }
                }
            }

            // ---- online softmax (native exp) ----
            float tmax[4];
            #pragma unroll
            for (int i = 0; i < 4; ++i)
                tmax[i] = fmaxf(fmaxf(sv[0][i], sv[1][i]), fmaxf(sv[2][i], sv[3][i]));
            #pragma unroll
            for (int off = 1; off < 16; off <<= 1)
                #pragma unroll
                for (int i = 0; i < 4; ++i)
                    tmax[i] = fmaxf(tmax[i], __shfl_xor(tmax[i], off));
            float mnew[4], corr[4];
            #pragma unroll
            for (int i = 0; i < 4; ++i) {
                mnew[i] = fmaxf(mrow[i], tmax[i]);
                corr[i] = __expf(mrow[i] - mnew[i]);
            }
            float p[4][4];
            float rsum[4] = {};
            #pragma unroll
            for (int nf = 0; nf < 4; ++nf)
                #pragma unroll
                for (int i = 0; i < 4; ++i) {
                    p[nf][i] = __expf(sv[nf][i] - mnew[i]);
                    rsum[i] += p[nf][i];
                }
            #pragma unroll
            for (int off = 1; off < 16; off <<= 1)
                #pragma unroll
                for (int i = 0; i < 4; ++i)
                    rsum[i] += __shfl_xor(rsum[i], off);
            #pragma unroll
            for (int i = 0; i < 4; ++i) {
                lrow[i] = lrow[i] * corr[i] + rsum[i];
                mrow[i] = mnew[i];
            }
            #pragma unroll
            for (int df = 0; df < 4; ++df)
                #pragma unroll
                for (int i = 0; i < 4; ++i)
                    oa[df][i] *= corr[i];

            // ---- write P (per-wave [16 q][72 kv], hi/lo) ----
            #pragma unroll
            for (int nf = 0; nf < 4; ++nf) {
                const int kv = 16*nf + r;
                #pragma unroll
                for (int i = 0; i < 4; ++i) {
                    const ushort_t phb = f2bf(p[nf][i]);
                    Ph[(w*16 + 4*g + i) * 72 + kv] = phb;
                    Pl[(w*16 + 4*g + i) * 72 + kv] = f2bf(p[nf][i] - bf2f(phb));
                }
            }
            lgkm0();   // P writes visible to this wave's reads

            // ---- PV: O += P·V, bf16x3, V frags from LDS ----
            #pragma unroll
            for (int ks = 0; ks < 2; ++ks) {
                const bf16x8 ph = *reinterpret_cast<const bf16x8*>(&Ph[(w*16 + r) * 72 + 32*ks + 8*g]);
                const bf16x8 pl = *reinterpret_cast<const bf16x8*>(&Pl[(w*16 + r) * 72 + 32*ks + 8*g]);
                #pragma unroll
                for (int df = 0; df < 4; ++df) {
                    const int vrow = 16*df + r;
                    const unsigned voff = (unsigned)(vrow * 128)
                        + (((unsigned)(ks*64 + g*16)) ^ ((unsigned)((vrow & 7) << 4)));
                    const bf16x8 vhf = *reinterpret_cast<const bf16x8*>((const char*)Vhi + voff);
                    const bf16x8 vlf = *reinterpret_cast<const bf16x8*>((const char*)Vlo + voff);
                    oa[df] = __builtin_amdgcn_mfma_f32_16x16x32_bf16(ph, vhf, oa[df], 0, 0, 0);
                    oa[df] = __builtin_amdgcn_mfma_f32_16x16x32_bf16(pl, vhf, oa[df], 0, 0, 0);
                    oa[df] = __builtin_amdgcn_mfma_f32_16x16x32_bf16(ph, vlf, oa[df], 0, 0, 0);
                }
            }

            // ---- commit staged registers to LDS for next tile ----
            if (kt < qt) {
                __syncthreads();                   // all reads of tile kt done
                *reinterpret_cast<bf16x8*>(&Khi[d0])        = stg[0];
                *reinterpret_cast<bf16x8*>(&Khi[d0 + 2048]) = stg[1];
                *reinterpret_cast<bf16x8*>(&Klo[d0])        = stg[2];
                *reinterpret_cast<bf16x8*>(&Klo[d0 + 2048]) = stg[3];
                *reinterpret_cast<bf16x8*>(&Vhi[d0])        = stg[4];
                *reinterpret_cast<bf16x8*>(&Vhi[d0 + 2048]) = stg[5];
                *reinterpret_cast<bf16x8*>(&Vlo[d0])        = stg[6];
                *reinterpret_cast<bf16x8*>(&Vlo[d0 + 2048]) = stg[7];
                __syncthreads();                   // writes visible
            }
        }

        // ---- epilogue: hi/lo split of O / l ----
        #pragma unroll
        for (int i = 0; i < 4; ++i) {
            const float inv = 1.0f / lrow[i];
            const size_t row = (rowbase + q0 + 16*w + 4*g + i) * (size_t)M_ + hoff;
            #pragma unroll
            for (int df = 0; df < 4; ++df) {
                const float v = oa[df][i] * inv;
                const ushort_t hb = f2bf(v);
                ohi[row + 16*df + r] = hb;
                olo[row + 16*df + r] = f2bf(v - bf2f(hb));
            }
        }
    }
}

// ---------------------------------------------------------------------------
// Router + deepspeed dispatch bookkeeping (exact, f32).
// ---------------------------------------------------------------------------
__global__ __launch_bounds__(256) void gate_kernel(const float* __restrict__ h2,
                                                   const float* __restrict__ wg,
                                                   int* __restrict__ gidx,
                                                   float* __restrict__ gtop)
{
    const int s = blockIdx.x;
    const int e = threadIdx.x >> 5;
    const int l = threadIdx.x & 31;
    const float* row = h2 + (size_t)s * M_;
    float acc = 0.0f;
    for (int m = l; m < M_; m += 32) acc = fmaf(row[m], wg[m * E_ + e], acc);
    #pragma unroll
    for (int off = 16; off > 0; off >>= 1) acc += __shfl_down(acc, off, 32);
    __shared__ float lg[E_];
    if (l == 0) lg[e] = acc;
    __syncthreads();
    if (threadIdx.x == 0) {
        float mx = lg[0]; int bi = 0;
        #pragma unroll
        for (int i = 1; i < E_; ++i) { if (lg[i] > mx) { mx = lg[i]; bi = i; } }
        float den = 0.0f;
        #pragma unroll
        for (int i = 0; i < E_; ++i) den += expf(lg[i] - mx);
        gidx[s] = bi;
        gtop[s] = 1.0f / den;
    }
}

__global__ __launch_bounds__(1024) void scan_kernel(const int* __restrict__ gidx,
                                                    const float* __restrict__ gtop,
                                                    float* __restrict__ gate_val,
                                                    int* __restrict__ token_at)
{
    __shared__ int hist[1024][E_];
    const int tid = threadIdx.x;
    for (int i = tid; i < E_ * C_; i += 1024) token_at[i] = -1;
    int my[8];
    #pragma unroll
    for (int t = 0; t < 8; ++t) my[t] = gidx[tid * 8 + t];
    #pragma unroll
    for (int e = 0; e < E_; ++e) {
        int c = 0;
        #pragma unroll
        for (int t = 0; t < 8; ++t) c += (my[t] == e) ? 1 : 0;
        hist[tid][e] = c;
    }
    __syncthreads();
    if (tid < E_) {
        int run = 0;
        for (int t = 0; t < 1024; ++t) {
            const int v = hist[t][tid];
            hist[t][tid] = run;
            run += v;
        }
    }
    __syncthreads();
    #pragma unroll
    for (int t = 0; t < 8; ++t) {
        const int s = tid * 8 + t;
        const int e = my[t];
        const int p = hist[tid][e];
        hist[tid][e] = p + 1;
        const bool keep = (p < C_);
        gate_val[s] = keep ? gtop[s] : 0.0f;
        if (keep) token_at[e * C_ + p] = s;
    }
}

__global__ __launch_bounds__(256) void dispatch_bf16_kernel(const float* __restrict__ h2,
                                                            const int* __restrict__ token_at,
                                                            ushort_t* __restrict__ disp)
{
    const int ec = blockIdx.x;
    const int s = token_at[ec];
    ushort4* dst = reinterpret_cast<ushort4*>(disp + (size_t)ec * M_);
    if (s >= 0) {
        const float4 v = reinterpret_cast<const float4*>(h2 + (size_t)s * M_)[threadIdx.x];
        dst[threadIdx.x] = make_ushort4(f2bf(v.x), f2bf(v.y), f2bf(v.z), f2bf(v.w));
    } else {
        dst[threadIdx.x] = make_ushort4(0, 0, 0, 0);
    }
}

// Transpose+convert: in[e][R][Cc] f32 -> out[e][Cc][R] bf16.
__global__ __launch_bounds__(256) void transpose_bf16_kernel(const float* __restrict__ in,
                                                             ushort_t* __restrict__ outp,
                                                             int R, int Cc)
{
    __shared__ float tile[32][33];
    const int e = blockIdx.z;
    in   += (size_t)e * R * Cc;
    outp += (size_t)e * R * Cc;
    const int tx = threadIdx.x & 31, ty0 = threadIdx.x >> 5;
    const int c0 = blockIdx.x * 32, r0 = blockIdx.y * 32;
    #pragma unroll
    for (int i = 0; i < 4; ++i)
        tile[ty0 + 8*i][tx] = in[(size_t)(r0 + ty0 + 8*i) * Cc + c0 + tx];
    __syncthreads();
    #pragma unroll
    for (int i = 0; i < 4; ++i)
        outp[(size_t)(c0 + ty0 + 8*i) * R + r0 + tx] = f2bf(tile[tx][ty0 + 8*i]);
}

// ---------------------------------------------------------------------------
// bf16 MFMA GEMM (MoE FFN, post-router) — unchanged, verified.
// ---------------------------------------------------------------------------
template<int EPI>
__global__ __launch_bounds__(256) void gemm_mfma(
    const ushort_t* __restrict__ A, const ushort_t* __restrict__ Bt,
    const float* __restrict__ bias,
    const int* __restrict__ token_at, const float* __restrict__ gate_val,
    void* __restrict__ Cout, int N, int K,
    long strA, long strB, long strBias, long strC)
{
    const int e = blockIdx.z;
    A    += (size_t)e * (size_t)strA;
    Bt   += (size_t)e * (size_t)strB;
    bias += (size_t)e * (size_t)strBias;

    __shared__ ushort_t As[128 * 32];
    __shared__ ushort_t Bs[128 * 32];

    const int t  = threadIdx.x;
    const int l  = t & 63;
    const int wv = t >> 6;
    const int wm = (wv & 1) * 64, wn = (wv >> 1) * 64;
    const int fr = l & 15, fk = (l >> 4) * 8;
    const int m0 = blockIdx.y * 128, n0 = blockIdx.x * 128;

    const ushort_t* gA = A + (size_t)(m0 + (t >> 2)) * K + (t & 3) * 8;
    const ushort_t* gB = Bt + (size_t)(n0 + (t >> 2)) * K + (t & 3) * 8;
    ushort_t* lA = As + wv * 512;
    ushort_t* lB = Bs + wv * 512;

    f32x4 acc[4][4] = {};

    for (int k0 = 0; k0 < K; k0 += 32) {
        __syncthreads();
        gload_lds16(gA + k0, lA);
        gload_lds16(gA + k0 + (size_t)64 * K, lA + 2048);
        gload_lds16(gB + k0, lB);
        gload_lds16(gB + k0 + (size_t)64 * K, lB + 2048);
        __syncthreads();
        bf16x8 af[4], bfr[4];
        #pragma unroll
        for (int i = 0; i < 4; ++i)
            af[i] = *reinterpret_cast<const bf16x8*>(&As[(wm + i*16 + fr) * 32 + fk]);
        #pragma unroll
        for (int i = 0; i < 4; ++i)
            bfr[i] = *reinterpret_cast<const bf16x8*>(&Bs[(wn + i*16 + fr) * 32 + fk]);
        #pragma unroll
        for (int mi = 0; mi < 4; ++mi) {
            #pragma unroll
            for (int ni = 0; ni < 4; ++ni)
                acc[mi][ni] = __builtin_amdgcn_mfma_f32_16x16x32_bf16(
                    af[mi], bfr[ni], acc[mi][ni], 0, 0, 0);
        }
    }

    const int l4 = (l >> 4) * 4;
    if (EPI == 0) {
        ushort_t* Cc = (ushort_t*)Cout + (size_t)e * (size_t)strC;
        #pragma unroll
        for (int ni = 0; ni < 4; ++ni) {
            const int cl = n0 + wn + ni*16 + fr;
            const float bb = bias[cl];
            #pragma unroll
            for (int mi = 0; mi < 4; ++mi) {
                #pragma unroll
                for (int i = 0; i < 4; ++i) {
                    const int rr = m0 + wm + mi*16 + l4 + i;
                    Cc[(size_t)rr * N + cl] = f2bf(gelu_exact(acc[mi][ni][i] + bb));
                }
            }
        }
    } else {
        float* Co = (float*)Cout;
        const int* ta = token_at + e * C_;
        #pragma unroll
        for (int mi = 0; mi < 4; ++mi) {
            #pragma unroll
            for (int i = 0; i < 4; ++i) {
                const int rr = m0 + wm + mi*16 + l4 + i;
                const int s = ta[rr];
                if (s >= 0) {
                    const float gvl = gate_val[s];
                    #pragma unroll
                    for (int ni = 0; ni < 4; ++ni) {
                        const int cl = n0 + wn + ni*16 + fr;
                        Co[(size_t)s * N + cl] += gvl * (acc[mi][ni][i] + bias[cl]);
                    }
                }
            }
        }
    }
}

// ---------------------------------------------------------------------------
extern "C" void kernel_launch(void* const* d_in, const int* in_sizes, int n_in,
                              void* d_out, int out_size, void* d_ws, size_t ws_size,
                              hipStream_t stream)
{
    const float* x    = (const float*)d_in[0];
    const float* ln1g = (const float*)d_in[1];
    const float* ln1b = (const float*)d_in[2];
    const float* Wqkv = (const float*)d_in[3];
    const float* bqkv = (const float*)d_in[4];
    const float* Wout = (const float*)d_in[5];
    const float* bout = (const float*)d_in[6];
    const float* ln2g = (const float*)d_in[7];
    const float* ln2b = (const float*)d_in[8];
    const float* wg   = (const float*)d_in[9];
    const float* w1   = (const float*)d_in[10];
    const float* b1   = (const float*)d_in[11];
    const float* w2   = (const float*)d_in[12];
    const float* b2   = (const float*)d_in[13];
    float* out = (float*)d_out;

    // Workspace (MiB offsets), lifetime-scheduled. Peak ~196 MiB.
    char* ws = (char*)d_ws;
    ushort_t* ahi   = (ushort_t*)ws;
    ushort_t* alo   = (ushort_t*)(ws + ((size_t)16  << 20));
    float*    buf_h = (float*)ws;
    ushort_t* qkvh  = (ushort_t*)(ws + ((size_t)32  << 20));
    ushort_t* qkvl  = (ushort_t*)(ws + ((size_t)80  << 20));
    ushort_t* vth   = (ushort_t*)(ws + ((size_t)128 << 20));
    ushort_t* vtl   = (ushort_t*)(ws + ((size_t)144 << 20));
    ushort_t* ohi   = (ushort_t*)(ws + ((size_t)160 << 20));
    ushort_t* olo   = (ushort_t*)(ws + ((size_t)176 << 20));
    ushort_t* wqh   = (ushort_t*)(ws + ((size_t)128 << 20));   // ph1 only
    ushort_t* wql   = (ushort_t*)(ws + ((size_t)134 << 20));   // ph1 only
    ushort_t* woh   = (ushort_t*)(ws + ((size_t)192 << 20));
    ushort_t* wol   = (ushort_t*)(ws + ((size_t)194 << 20));
    ushort_t* w1t   = (ushort_t*)(ws + ((size_t)32  << 20));
    ushort_t* w2t   = (ushort_t*)(ws + ((size_t)32  << 20));
    ushort_t* dispb = (ushort_t*)(ws + ((size_t)96  << 20));
    ushort_t* h1b   = (ushort_t*)(ws + ((size_t)112 << 20));
    float*    buf_gtop = (float*)(ws + ((size_t)196 << 20));
    float*    buf_gv   = buf_gtop + S_;
    int*      buf_idx  = (int*)(buf_gv + S_);
    int*      buf_ta   = buf_idx + S_;

    // --- pre-router path (f32-grade via bf16x3 MFMA) ---
    split_kernel<<<(3*M_*M_/4 + 255)/256, 256, 0, stream>>>(Wqkv, wqh, wql, 3*M_*M_/4);
    split_kernel<<<(M_*M_/4 + 255)/256, 256, 0, stream>>>(Wout, woh, wol, M_*M_/4);
    ln_split_kernel<<<S_, 256, 0, stream>>>(x, ln1g, ln1b, ahi, alo);
    gemm_bf16x3<2><<<dim3(3*M_/128, S_/128, 1), 256, 0, stream>>>(
        ahi, alo, wqh, wql, bqkv, nullptr, qkvh, qkvl, 3*M_, M_);
    vtrans_kernel<<<dim3(T_/64, H_, B_), 256, 0, stream>>>(qkvh, qkvl, vth, vtl);
    attn_mfma_kernel<<<dim3(768, 1, 1), 256, 0, stream>>>(qkvh, qkvl, vth, vtl, ohi, olo);
    gemm_bf16x3<1><<<dim3(M_/128, S_/128, 1), 256, 0, stream>>>(
        ohi, olo, woh, wol, bout, x, out, nullptr, M_, M_);

    // --- router (exact f32) ---
    ln_kernel<<<S_, 256, 0, stream>>>(out, ln2g, ln2b, buf_h);
    gate_kernel<<<S_, 256, 0, stream>>>(buf_h, wg, buf_idx, buf_gtop);
    scan_kernel<<<1, 1024, 0, stream>>>(buf_idx, buf_gtop, buf_gv, buf_ta);
    dispatch_bf16_kernel<<<E_*C_, 256, 0, stream>>>(buf_h, buf_ta, dispb);

    // --- MoE FFN (bf16 MFMA, post-router) ---
    transpose_bf16_kernel<<<dim3(F_/32, M_/32, E_), 256, 0, stream>>>(w1, w1t, M_, F_);
    gemm_mfma<0><<<dim3(F_/128, C_/128, E_), 256, 0, stream>>>(
        dispb, w1t, b1, nullptr, nullptr, h1b, F_, M_,
        (long)C_*M_, (long)F_*M_, (long)F_, (long)C_*F_);
    transpose_bf16_kernel<<<dim3(M_/32, F_/32, E_), 256, 0, stream>>>(w2, w2t, F_, M_);
    gemm_mfma<1><<<dim3(M_/128, C_/128, E_), 256, 0, stream>>>(
        h1b, w2t, b2, buf_ta, buf_gv, out, M_, F_,
        (long)C_*F_, (long)M_*F_, (long)M_, 0);
}